// Round 4
// baseline (1385.506 us; speedup 1.0000x reference)
//
#include <hip/hip_runtime.h>
#include <hip/hip_bf16.h>

#define Bb 8
#define Cc 256
#define Nn 4096
#define Dd 32

typedef short bf16x8 __attribute__((ext_vector_type(8)));
typedef short bf16x4 __attribute__((ext_vector_type(4)));
typedef float f32x4 __attribute__((ext_vector_type(4)));
typedef unsigned int u32;

__device__ __forceinline__ void glds16(const void* g, void* l) {
    __builtin_amdgcn_global_load_lds(
        (const __attribute__((address_space(1))) unsigned int*)g,
        (__attribute__((address_space(3))) unsigned int*)l, 16, 0, 0);
}

// pack two f32 -> one u32 of 2 bf16 (low = a). Compiler fuses to v_cvt_pk_bf16_f32.
__device__ __forceinline__ u32 pkbf16(float a, float b) {
    return ((u32)__bfloat16_as_ushort(__float2bfloat16(b)) << 16) |
           (u32)__bfloat16_as_ushort(__float2bfloat16(a));
}

// ---------------- transpose-convert x -> x_t[b][n][c] bf16, fused stats ----------------
__global__ __launch_bounds__(256) void convt_kernel(
    const float* __restrict__ x, __hip_bfloat16* __restrict__ x_t,
    float* __restrict__ sum_ws, float* __restrict__ sumsq_ws)
{
    __shared__ __hip_bfloat16 tile[64][68];
    const int n0 = blockIdx.x * 64, c0 = blockIdx.y * 64, b = blockIdx.z;
    const int t = threadIdx.x;

#pragma unroll
    for (int i = 0; i < 4; i++) {
        int id = i * 256 + t;
        int row = id >> 4, col4 = id & 15;
        float4 v = *(const float4*)(x + ((size_t)(b * Cc + c0 + row)) * Nn + n0 + col4 * 4);
        bf16x4 bv;
        bv[0] = __bfloat16_as_short(__float2bfloat16(v.x));
        bv[1] = __bfloat16_as_short(__float2bfloat16(v.y));
        bv[2] = __bfloat16_as_short(__float2bfloat16(v.z));
        bv[3] = __bfloat16_as_short(__float2bfloat16(v.w));
        *(bf16x4*)((void*)&tile[row][col4 * 4]) = bv;
        float ls  = v.x + v.y + v.z + v.w;
        float ls2 = v.x * v.x + v.y * v.y + v.z * v.z + v.w * v.w;
        ls  += __shfl_xor(ls, 1, 16);  ls2 += __shfl_xor(ls2, 1, 16);
        ls  += __shfl_xor(ls, 2, 16);  ls2 += __shfl_xor(ls2, 2, 16);
        ls  += __shfl_xor(ls, 4, 16);  ls2 += __shfl_xor(ls2, 4, 16);
        ls  += __shfl_xor(ls, 8, 16);  ls2 += __shfl_xor(ls2, 8, 16);
        if ((t & 15) == 0) {
            atomicAdd(&sum_ws[b * Cc + c0 + row], ls);
            atomicAdd(&sumsq_ws[b * Cc + c0 + row], ls2);
        }
    }
    __syncthreads();
#pragma unroll
    for (int i = 0; i < 2; i++) {
        int id = i * 256 + t;
        int nl = id >> 3, cg = id & 7;
        bf16x8 o;
#pragma unroll
        for (int j = 0; j < 8; j++) o[j] = __bfloat16_as_short(tile[cg * 8 + j][nl]);
        *(bf16x8*)(x_t + ((size_t)(b * Nn + n0 + nl)) * Cc + c0 + cg * 8) = o;
    }
}

// ---------------- W -> bf16 frag-block layout (run once, 5 blocks) ----------------
__global__ __launch_bounds__(256) void wconv_kernel(
    const float* __restrict__ Wq, const float* __restrict__ Wk, const float* __restrict__ Wv,
    __hip_bfloat16* __restrict__ w_bf)
{
    const int ct = blockIdx.x;
    const int t = threadIdx.x;
#pragma unroll
    for (int i = 0; i < 8; i++) {
        int g = i * 256 + t;
        int row = g >> 5, c8 = g & 31;
        int c0 = c8 * 8;
        int grow = ct * 64 + row;
        const float* src;
        if (grow < 32)       src = Wq + (size_t)grow * Cc + c0;
        else if (grow < 64)  src = Wk + (size_t)(grow - 32) * Cc + c0;
        else                 src = Wv + (size_t)(grow - 64) * Cc + c0;
        float4 v0 = *(const float4*)src;
        float4 v1 = *(const float4*)(src + 4);
        bf16x8 o;
        o[0] = __bfloat16_as_short(__float2bfloat16(v0.x));
        o[1] = __bfloat16_as_short(__float2bfloat16(v0.y));
        o[2] = __bfloat16_as_short(__float2bfloat16(v0.z));
        o[3] = __bfloat16_as_short(__float2bfloat16(v0.w));
        o[4] = __bfloat16_as_short(__float2bfloat16(v1.x));
        o[5] = __bfloat16_as_short(__float2bfloat16(v1.y));
        o[6] = __bfloat16_as_short(__float2bfloat16(v1.z));
        o[7] = __bfloat16_as_short(__float2bfloat16(v1.w));
        int kchunk = c0 >> 5, qd = (c0 & 31) >> 3, cg = row >> 4, rl = row & 15;
        *(bf16x8*)(w_bf + ((size_t)ct * 32 + kchunk * 4 + cg) * 512 + (qd * 16 + rl) * 8) = o;
    }
}

// ---------------- MFMA projection ----------------
__global__ __launch_bounds__(256, 2) void proj_kernel(
    const __hip_bfloat16* __restrict__ x_t, const __hip_bfloat16* __restrict__ w_bf,
    const float* __restrict__ bq, const float* __restrict__ bk, const float* __restrict__ bv,
    __hip_bfloat16* __restrict__ q_ws, __hip_bfloat16* __restrict__ k_ws,
    __hip_bfloat16* __restrict__ v_ws)
{
    __shared__ __hip_bfloat16 ldsX[32 * 512];
    __shared__ __hip_bfloat16 ldsW[32 * 512];

    const int n0 = blockIdx.x * 64;
    const int ct = blockIdx.y;
    const int b  = blockIdx.z;
    const int t = threadIdx.x;
    const int w = t >> 6, lane = t & 63, quad = lane >> 4, l15 = lane & 15;

#pragma unroll
    for (int j = 0; j < 8; j++) {
        int idx = w * 8 + j;
        int kchunk = idx >> 2, ngrp = idx & 3;
        glds16(x_t + ((size_t)(b * Nn + n0 + ngrp * 16 + l15)) * Cc + kchunk * 32 + quad * 8,
               ldsX + idx * 512);
        glds16(w_bf + ((size_t)ct * 32 + idx) * 512 + lane * 8, ldsW + idx * 512);
    }
    __syncthreads();

    f32x4 acc[4];
#pragma unroll
    for (int cg = 0; cg < 4; cg++) {
        int gcol = ct * 64 + cg * 16 + l15;
        float bias = (gcol < 32) ? bq[gcol] : (gcol < 64 ? bk[gcol - 32] : bv[gcol - 64]);
        acc[cg] = (f32x4){bias, bias, bias, bias};
    }

#pragma unroll
    for (int kchunk = 0; kchunk < 8; kchunk++) {
        bf16x8 a = *(const bf16x8*)(ldsX + ((kchunk * 4 + w) * 64 + lane) * 8);
#pragma unroll
        for (int cg = 0; cg < 4; cg++) {
            bf16x8 bw = *(const bf16x8*)(ldsW + ((kchunk * 4 + cg) * 64 + lane) * 8);
            acc[cg] = __builtin_amdgcn_mfma_f32_16x16x32_bf16(a, bw, acc[cg], 0, 0, 0);
        }
    }

#pragma unroll
    for (int cg = 0; cg < 4; cg++) {
        int gcol = ct * 64 + cg * 16 + l15;
        int nb = n0 + w * 16 + quad * 4;
        if (gcol < 64) {
            __hip_bfloat16* dst = (gcol < 32) ? q_ws : k_ws;
            int d = gcol & 31;
#pragma unroll
            for (int r = 0; r < 4; r++)
                dst[((size_t)(b * Nn + nb + r)) * Dd + d] = __float2bfloat16(acc[cg][r]);
        } else {
            int c = gcol - 64;
            bf16x4 o;
#pragma unroll
            for (int r = 0; r < 4; r++) o[r] = __bfloat16_as_short(__float2bfloat16(acc[cg][r]));
            *(bf16x4*)(v_ws + ((size_t)(b * Cc + c)) * Nn + nb) = o;
        }
    }
}

// ---------------- SE gate MLP ----------------
__global__ __launch_bounds__(256) void gate_kernel(
    const float* __restrict__ sum_ws, const float* __restrict__ sumsq_ws,
    const float* __restrict__ W1, const float* __restrict__ W2,
    const float* __restrict__ lamb, float* __restrict__ coef)
{
    int b = blockIdx.x;
    __shared__ float inp[2 * Cc];
    __shared__ float h[32];
    int t = threadIdx.x;
    float s  = sum_ws[b * Cc + t];
    float s2 = sumsq_ws[b * Cc + t];
    float m   = s / Nn;
    float var = (s2 - (float)Nn * m * m) / (float)(Nn - 1);
    inp[t]      = m;
    inp[Cc + t] = sqrtf(fmaxf(var, 0.f));
    __syncthreads();
    if (t < 32) {
        float a = 0.f;
        for (int i = 0; i < 2 * Cc; i++) a += W1[t * (2 * Cc) + i] * inp[i];
        h[t] = fmaxf(a, 0.f);
    }
    __syncthreads();
    float g = 0.f;
#pragma unroll
    for (int r = 0; r < 32; r++) g += W2[t * 32 + r] * h[r];
    float a = 1.f / (1.f + __expf(-g));
    coef[b * Cc + t] = 1.f + lamb[0] * a;
}

// ---------------- flash attention v8: n-split waves + S(it+1)/PV(it) pipeline ----------
// v7 post-mortem: iter time ~= SUM of pipes (serialized) and LDS was the largest
// term (8x V-read redundancy). v8: 8 waves = 4 m-pairs x 2 n-parities. Wave owns
// 2 m-frags (32m) x 256c x HALF the n (32 of 64). Zero duplicated work anywhere:
// S 4 MFMA/wave, exp 16/thread (device minimum), PV 32 MFMA/wave, V-reads 16/wave
// (each feeds 2 MFMAs), K-reads 2. Permlane pairing needs adjacent tt: parity owns
// {2p, 2p+1} - exactly the verified v6/v7 mapping with nc = p.
// Pipelining: S(it+1)/exp/pack computed BEFORE PV(it) (K slab for it+1 is resident,
// staged >=1 barrier earlier) so exp VALU + 4 S-MFMAs overlap the PV block.
// End: (w, w^4) pairs hold disjoint-n partial sums of the same output -> one-time
// f32 acc exchange through LDS (2 rounds x 64KB) + lsum exchange, then each wave
// finalizes+stores its cf-half.
__global__ __launch_bounds__(512, 2) void attn_kernel(
    const __hip_bfloat16* __restrict__ q_ws, const __hip_bfloat16* __restrict__ k_ws,
    const __hip_bfloat16* __restrict__ v_ws, const float* __restrict__ coef,
    const float* __restrict__ x, const float* __restrict__ gamma_p,
    float* __restrict__ out)
{
    extern __shared__ __hip_bfloat16 smem[];
    __hip_bfloat16* vbuf0 = smem;              // 16384 el (32 KB) each
    __hip_bfloat16* vbuf1 = smem + 16384;
    __hip_bfloat16* kbuf0 = smem + 32768;      // 4096 el (8 KB) each
    __hip_bfloat16* kbuf1 = smem + 36864;      // total 40960 el = 81920 B

    const int b  = blockIdx.x & 7;             // XCD-locality swizzle
    const int m0 = (blockIdx.x >> 3) * 128;
    const int t = threadIdx.x;
    const int w = t >> 6, lane = t & 63, quad = lane >> 4, l15 = lane & 15;
    const int p = w >> 2, pw = w & 3;          // n-parity, m-pair index

    // Q fragments (B-operand) for this wave's 2 m-frags {2pw, 2pw+1}
    const bf16x8 aq0 = *(const bf16x8*)(q_ws + ((size_t)(b * Nn + m0 + (2 * pw)     * 16 + l15)) * Dd + quad * 8);
    const bf16x8 aq1 = *(const bf16x8*)(q_ws + ((size_t)(b * Nn + m0 + (2 * pw + 1) * 16 + l15)) * Dd + quad * 8);

    // V staging: wave w stages frags idx = w*4+j (idx = nchunk*16 + cfrag), linear LDS
    const __hip_bfloat16* vsrc[4];
#pragma unroll
    for (int j = 0; j < 4; j++) {
        int idx = w * 4 + j;
        int ch = idx >> 4, tc = idx & 15;
        vsrc[j] = v_ws + ((size_t)(b * Cc + tc * 16 + l15)) * Nn + ch * 32 + quad * 8;
    }
    // K staging with sigma row permutation (swap bits 2<->3 of l15); slab = 128 n rows
    const int sl15 = (l15 & 3) | ((l15 & 4) << 1) | ((l15 & 8) >> 1);
    const __hip_bfloat16* ksrc = k_ws + ((size_t)(b * Nn + w * 16 + sl15)) * Dd + quad * 8;

    // prestage V(0) + K slab 0; barrier drains DMAs (vmcnt(0) at barrier)
#pragma unroll
    for (int j = 0; j < 4; j++) glds16(vsrc[j], vbuf0 + (w * 4 + j) * 512);
    glds16(ksrc, kbuf0 + w * 512);
    __syncthreads();

    f32x4 acc[2][16];
#pragma unroll
    for (int i = 0; i < 2; i++)
#pragma unroll
        for (int j = 0; j < 16; j++) acc[i][j] = (f32x4){0.f, 0.f, 0.f, 0.f};
    float lsum0 = 0.f, lsum1 = 0.f;

    const int NIT = Nn / 64;

    // prologue: S(0) -> pc (current P regs)
    u32 pc0[2][2], pc1[2][2];
#pragma unroll
    for (int j = 0; j < 2; j++) {
        bf16x8 ak = *(const bf16x8*)(kbuf0 + ((2 * p + j) * 64 + lane) * 8);
        f32x4 s0 = __builtin_amdgcn_mfma_f32_16x16x32_bf16(ak, aq0, (f32x4){0.f,0.f,0.f,0.f}, 0, 0, 0);
        f32x4 s1 = __builtin_amdgcn_mfma_f32_16x16x32_bf16(ak, aq1, (f32x4){0.f,0.f,0.f,0.f}, 0, 0, 0);
        float a0 = __expf(s0[0]), a1 = __expf(s0[1]), a2 = __expf(s0[2]), a3 = __expf(s0[3]);
        lsum0 += (a0 + a1) + (a2 + a3);
        pc0[j][0] = pkbf16(a0, a1); pc0[j][1] = pkbf16(a2, a3);
        float b0 = __expf(s1[0]), b1 = __expf(s1[1]), b2 = __expf(s1[2]), b3 = __expf(s1[3]);
        lsum1 += (b0 + b1) + (b2 + b3);
        pc1[j][0] = pkbf16(b0, b1); pc1[j][1] = pkbf16(b2, b3);
    }

    for (int it = 0; it < NIT; it++) {
        // ---- prefetch next tiles into the other buffers (overlaps whole iter) ----
        if (it + 1 < NIT) {
            __hip_bfloat16* vn = ((it + 1) & 1) ? vbuf1 : vbuf0;
#pragma unroll
            for (int j = 0; j < 4; j++)
                glds16(vsrc[j] + (size_t)(it + 1) * 64, vn + (w * 4 + j) * 512);
        }
        if ((it & 1) == 0 && it + 2 < NIT) {
            int sl = (it >> 1) + 1;
            glds16(ksrc + (size_t)(sl * 128) * Dd, ((sl & 1) ? kbuf1 : kbuf0) + w * 512);
        }

        // ---- B-frags for PV(it) from pc via permlane32_swap (nc = p) ----
        auto g0 = __builtin_amdgcn_permlane32_swap(pc0[0][0], pc0[1][0], false, false);
        auto g1 = __builtin_amdgcn_permlane32_swap(pc0[0][1], pc0[1][1], false, false);
        auto h0 = __builtin_amdgcn_permlane32_swap(pc1[0][0], pc1[1][0], false, false);
        auto h1 = __builtin_amdgcn_permlane32_swap(pc1[0][1], pc1[1][1], false, false);
        union { u32 uw[4]; bf16x8 v; } bp0, bp1;
        bp0.uw[0] = g0[0]; bp0.uw[1] = g1[0]; bp0.uw[2] = g0[1]; bp0.uw[3] = g1[1];
        bp1.uw[0] = h0[0]; bp1.uw[1] = h1[0]; bp1.uw[2] = h0[1]; bp1.uw[3] = h1[1];

        // ---- S(it+1) -> pn; overlaps PV MFMAs below (K slab resident; last iter
        // computes clamped garbage that is never consumed) ----
        u32 pn0[2][2], pn1[2][2];
        const int itn = (it + 1 < NIT) ? it + 1 : it;
        const __hip_bfloat16* kbn = (((itn >> 1) & 1) ? kbuf1 : kbuf0) + (itn & 1) * 2048;
        float nls0 = 0.f, nls1 = 0.f;
#pragma unroll
        for (int j = 0; j < 2; j++) {
            bf16x8 ak = *(const bf16x8*)(kbn + ((2 * p + j) * 64 + lane) * 8);
            f32x4 s0 = __builtin_amdgcn_mfma_f32_16x16x32_bf16(ak, aq0, (f32x4){0.f,0.f,0.f,0.f}, 0, 0, 0);
            f32x4 s1 = __builtin_amdgcn_mfma_f32_16x16x32_bf16(ak, aq1, (f32x4){0.f,0.f,0.f,0.f}, 0, 0, 0);
            float a0 = __expf(s0[0]), a1 = __expf(s0[1]), a2 = __expf(s0[2]), a3 = __expf(s0[3]);
            nls0 += (a0 + a1) + (a2 + a3);
            pn0[j][0] = pkbf16(a0, a1); pn0[j][1] = pkbf16(a2, a3);
            float b0 = __expf(s1[0]), b1 = __expf(s1[1]), b2 = __expf(s1[2]), b3 = __expf(s1[3]);
            nls1 += (b0 + b1) + (b2 + b3);
            pn1[j][0] = pkbf16(b0, b1); pn1[j][1] = pkbf16(b2, b3);
        }
        if (it + 1 < NIT) { lsum0 += nls0; lsum1 += nls1; }

        // ---- O^T += V P^T over this wave's n-half (kc = p) ----
        const __hip_bfloat16* vb = (it & 1) ? vbuf1 : vbuf0;
#pragma unroll
        for (int cf = 0; cf < 16; cf++) {
            bf16x8 av = *(const bf16x8*)(vb + ((p * 16 + cf) * 64 + lane) * 8);
            acc[0][cf] = __builtin_amdgcn_mfma_f32_16x16x32_bf16(av, bp0.v, acc[0][cf], 0, 0, 0);
            acc[1][cf] = __builtin_amdgcn_mfma_f32_16x16x32_bf16(av, bp1.v, acc[1][cf], 0, 0, 0);
        }

        // rotate P regs
#pragma unroll
        for (int j = 0; j < 2; j++)
#pragma unroll
            for (int k = 0; k < 2; k++) { pc0[j][k] = pn0[j][k]; pc1[j][k] = pn1[j][k]; }

        __syncthreads();  // dbuf rotation: all reads of cur buffers done; DMAs drained
    }

    // ---- cross-parity reduction: (w, w^4) hold disjoint-n partials of same output ----
    const int kk = p ? 8 : 0;      // cf half this wave finalizes
    const int ko = 8 - kk;         // cf half given to partner
    float* lex = (float*)(smem + 32768);   // bytes 65536..69632 (4 KB), disjoint from exv
    lex[w * 128 + lane]      = lsum0;
    lex[w * 128 + 64 + lane] = lsum1;
    f32x4* exv = (f32x4*)smem;             // bytes 0..65536: [w][j<8][lane] f32x4
#pragma unroll
    for (int mfi = 0; mfi < 2; mfi++) {
        __syncthreads();
#pragma unroll
        for (int j = 0; j < 8; j++) exv[(w * 8 + j) * 64 + lane] = acc[mfi][ko + j];
        __syncthreads();
#pragma unroll
        for (int j = 0; j < 8; j++) acc[mfi][kk + j] += exv[((w ^ 4) * 8 + j) * 64 + lane];
        if (mfi == 0) {
            lsum0 += lex[(w ^ 4) * 128 + lane];
            lsum1 += lex[(w ^ 4) * 128 + 64 + lane];
        }
    }

    // ---- epilogue: l[m] reduce over quads (m = l15 is lane-local), then store ----
    lsum0 += __shfl_xor(lsum0, 16); lsum0 += __shfl_xor(lsum0, 32);
    lsum1 += __shfl_xor(lsum1, 16); lsum1 += __shfl_xor(lsum1, 32);
    const float g = gamma_p[0];
    const float inv0 = g / lsum0, inv1 = g / lsum1;

#pragma unroll
    for (int j = 0; j < 8; j++) {
        int c0 = (kk + j) * 16 + quad * 4;
#pragma unroll
        for (int r = 0; r < 4; r++) {
            int c = c0 + r;
            float cfv = coef[b * Cc + c];
            size_t base = ((size_t)(b * Cc + c)) * Nn + m0 + (2 * pw) * 16 + l15;
            out[base]      = acc[0][kk + j][r] * inv0 + cfv * x[base];
            out[base + 16] = acc[1][kk + j][r] * inv1 + cfv * x[base + 16];
        }
    }
}

extern "C" void kernel_launch(void* const* d_in, const int* in_sizes, int n_in,
                              void* d_out, int out_size, void* d_ws, size_t ws_size,
                              hipStream_t stream) {
    const float* x     = (const float*)d_in[0];
    const float* Wq    = (const float*)d_in[1];
    const float* bq    = (const float*)d_in[2];
    const float* Wk    = (const float*)d_in[3];
    const float* bk    = (const float*)d_in[4];
    const float* Wv    = (const float*)d_in[5];
    const float* bv    = (const float*)d_in[6];
    const float* gamma = (const float*)d_in[7];
    const float* W1    = (const float*)d_in[8];
    const float* W2    = (const float*)d_in[9];
    const float* lamb  = (const float*)d_in[10];
    float* out = (float*)d_out;

    char* ws = (char*)d_ws;
    __hip_bfloat16* q_ws = (__hip_bfloat16*)ws;                       //  2 MB
    __hip_bfloat16* k_ws = (__hip_bfloat16*)(ws + (2u  << 20));       //  2 MB
    __hip_bfloat16* v_ws = (__hip_bfloat16*)(ws + (4u  << 20));       // 16 MB
    __hip_bfloat16* x_t  = (__hip_bfloat16*)(ws + (20u << 20));       // 16 MB
    float* sum_ws   = (float*)(ws + (36u << 20));
    float* sumsq_ws = sum_ws + Bb * Cc;
    float* coef     = sumsq_ws + Bb * Cc;
    __hip_bfloat16* w_bf = (__hip_bfloat16*)(ws + (37u << 20));       // 320 KB

    (void)hipFuncSetAttribute((const void*)attn_kernel,
                              hipFuncAttributeMaxDynamicSharedMemorySize, 81920);

    hipMemsetAsync(sum_ws, 0, 2 * Bb * Cc * sizeof(float), stream);
    wconv_kernel<<<5, 256, 0, stream>>>(Wq, Wk, Wv, w_bf);
    convt_kernel<<<dim3(Nn / 64, Cc / 64, Bb), 256, 0, stream>>>(x, x_t, sum_ws, sumsq_ws);
    proj_kernel<<<dim3(Nn / 64, 5, Bb), 256, 0, stream>>>(x_t, w_bf, bq, bk, bv, q_ws, k_ws, v_ws);
    gate_kernel<<<Bb, 256, 0, stream>>>(sum_ws, sumsq_ws, W1, W2, lamb, coef);
    attn_kernel<<<256, 512, 81920, stream>>>(q_ws, k_ws, v_ws, coef, x, gamma, out);
}

// Round 5
// 245.668 us; speedup vs baseline: 5.6398x; 5.6398x over previous
//
#include <hip/hip_runtime.h>
#include <hip/hip_bf16.h>

#define Bb 8
#define Cc 256
#define Nn 4096
#define Dd 32

typedef short bf16x8 __attribute__((ext_vector_type(8)));
typedef short bf16x4 __attribute__((ext_vector_type(4)));
typedef float f32x4 __attribute__((ext_vector_type(4)));
typedef unsigned int u32;

__device__ __forceinline__ void glds16(const void* g, void* l) {
    __builtin_amdgcn_global_load_lds(
        (const __attribute__((address_space(1))) unsigned int*)g,
        (__attribute__((address_space(3))) unsigned int*)l, 16, 0, 0);
}

// pack two f32 -> one u32 of 2 bf16 (low = a). Compiler fuses to v_cvt_pk_bf16_f32.
__device__ __forceinline__ u32 pkbf16(float a, float b) {
    return ((u32)__bfloat16_as_ushort(__float2bfloat16(b)) << 16) |
           (u32)__bfloat16_as_ushort(__float2bfloat16(a));
}

// ---------------- transpose-convert x -> x_t[b][n][c] bf16, fused stats ----------------
__global__ __launch_bounds__(256) void convt_kernel(
    const float* __restrict__ x, __hip_bfloat16* __restrict__ x_t,
    float* __restrict__ sum_ws, float* __restrict__ sumsq_ws)
{
    __shared__ __hip_bfloat16 tile[64][68];
    const int n0 = blockIdx.x * 64, c0 = blockIdx.y * 64, b = blockIdx.z;
    const int t = threadIdx.x;

#pragma unroll
    for (int i = 0; i < 4; i++) {
        int id = i * 256 + t;
        int row = id >> 4, col4 = id & 15;
        float4 v = *(const float4*)(x + ((size_t)(b * Cc + c0 + row)) * Nn + n0 + col4 * 4);
        bf16x4 bv;
        bv[0] = __bfloat16_as_short(__float2bfloat16(v.x));
        bv[1] = __bfloat16_as_short(__float2bfloat16(v.y));
        bv[2] = __bfloat16_as_short(__float2bfloat16(v.z));
        bv[3] = __bfloat16_as_short(__float2bfloat16(v.w));
        *(bf16x4*)((void*)&tile[row][col4 * 4]) = bv;
        float ls  = v.x + v.y + v.z + v.w;
        float ls2 = v.x * v.x + v.y * v.y + v.z * v.z + v.w * v.w;
        ls  += __shfl_xor(ls, 1, 16);  ls2 += __shfl_xor(ls2, 1, 16);
        ls  += __shfl_xor(ls, 2, 16);  ls2 += __shfl_xor(ls2, 2, 16);
        ls  += __shfl_xor(ls, 4, 16);  ls2 += __shfl_xor(ls2, 4, 16);
        ls  += __shfl_xor(ls, 8, 16);  ls2 += __shfl_xor(ls2, 8, 16);
        if ((t & 15) == 0) {
            atomicAdd(&sum_ws[b * Cc + c0 + row], ls);
            atomicAdd(&sumsq_ws[b * Cc + c0 + row], ls2);
        }
    }
    __syncthreads();
#pragma unroll
    for (int i = 0; i < 2; i++) {
        int id = i * 256 + t;
        int nl = id >> 3, cg = id & 7;
        bf16x8 o;
#pragma unroll
        for (int j = 0; j < 8; j++) o[j] = __bfloat16_as_short(tile[cg * 8 + j][nl]);
        *(bf16x8*)(x_t + ((size_t)(b * Nn + n0 + nl)) * Cc + c0 + cg * 8) = o;
    }
}

// ---------------- W -> bf16 frag-block layout (run once, 5 blocks) ----------------
__global__ __launch_bounds__(256) void wconv_kernel(
    const float* __restrict__ Wq, const float* __restrict__ Wk, const float* __restrict__ Wv,
    __hip_bfloat16* __restrict__ w_bf)
{
    const int ct = blockIdx.x;
    const int t = threadIdx.x;
#pragma unroll
    for (int i = 0; i < 8; i++) {
        int g = i * 256 + t;
        int row = g >> 5, c8 = g & 31;
        int c0 = c8 * 8;
        int grow = ct * 64 + row;
        const float* src;
        if (grow < 32)       src = Wq + (size_t)grow * Cc + c0;
        else if (grow < 64)  src = Wk + (size_t)(grow - 32) * Cc + c0;
        else                 src = Wv + (size_t)(grow - 64) * Cc + c0;
        float4 v0 = *(const float4*)src;
        float4 v1 = *(const float4*)(src + 4);
        bf16x8 o;
        o[0] = __bfloat16_as_short(__float2bfloat16(v0.x));
        o[1] = __bfloat16_as_short(__float2bfloat16(v0.y));
        o[2] = __bfloat16_as_short(__float2bfloat16(v0.z));
        o[3] = __bfloat16_as_short(__float2bfloat16(v0.w));
        o[4] = __bfloat16_as_short(__float2bfloat16(v1.x));
        o[5] = __bfloat16_as_short(__float2bfloat16(v1.y));
        o[6] = __bfloat16_as_short(__float2bfloat16(v1.z));
        o[7] = __bfloat16_as_short(__float2bfloat16(v1.w));
        int kchunk = c0 >> 5, qd = (c0 & 31) >> 3, cg = row >> 4, rl = row & 15;
        *(bf16x8*)(w_bf + ((size_t)ct * 32 + kchunk * 4 + cg) * 512 + (qd * 16 + rl) * 8) = o;
    }
}

// ---------------- MFMA projection ----------------
__global__ __launch_bounds__(256, 2) void proj_kernel(
    const __hip_bfloat16* __restrict__ x_t, const __hip_bfloat16* __restrict__ w_bf,
    const float* __restrict__ bq, const float* __restrict__ bk, const float* __restrict__ bv,
    __hip_bfloat16* __restrict__ q_ws, __hip_bfloat16* __restrict__ k_ws,
    __hip_bfloat16* __restrict__ v_ws)
{
    __shared__ __hip_bfloat16 ldsX[32 * 512];
    __shared__ __hip_bfloat16 ldsW[32 * 512];

    const int n0 = blockIdx.x * 64;
    const int ct = blockIdx.y;
    const int b  = blockIdx.z;
    const int t = threadIdx.x;
    const int w = t >> 6, lane = t & 63, quad = lane >> 4, l15 = lane & 15;

#pragma unroll
    for (int j = 0; j < 8; j++) {
        int idx = w * 8 + j;
        int kchunk = idx >> 2, ngrp = idx & 3;
        glds16(x_t + ((size_t)(b * Nn + n0 + ngrp * 16 + l15)) * Cc + kchunk * 32 + quad * 8,
               ldsX + idx * 512);
        glds16(w_bf + ((size_t)ct * 32 + idx) * 512 + lane * 8, ldsW + idx * 512);
    }
    __syncthreads();

    f32x4 acc[4];
#pragma unroll
    for (int cg = 0; cg < 4; cg++) {
        int gcol = ct * 64 + cg * 16 + l15;
        float bias = (gcol < 32) ? bq[gcol] : (gcol < 64 ? bk[gcol - 32] : bv[gcol - 64]);
        acc[cg] = (f32x4){bias, bias, bias, bias};
    }

#pragma unroll
    for (int kchunk = 0; kchunk < 8; kchunk++) {
        bf16x8 a = *(const bf16x8*)(ldsX + ((kchunk * 4 + w) * 64 + lane) * 8);
#pragma unroll
        for (int cg = 0; cg < 4; cg++) {
            bf16x8 bw = *(const bf16x8*)(ldsW + ((kchunk * 4 + cg) * 64 + lane) * 8);
            acc[cg] = __builtin_amdgcn_mfma_f32_16x16x32_bf16(a, bw, acc[cg], 0, 0, 0);
        }
    }

#pragma unroll
    for (int cg = 0; cg < 4; cg++) {
        int gcol = ct * 64 + cg * 16 + l15;
        int nb = n0 + w * 16 + quad * 4;
        if (gcol < 64) {
            __hip_bfloat16* dst = (gcol < 32) ? q_ws : k_ws;
            int d = gcol & 31;
#pragma unroll
            for (int r = 0; r < 4; r++)
                dst[((size_t)(b * Nn + nb + r)) * Dd + d] = __float2bfloat16(acc[cg][r]);
        } else {
            int c = gcol - 64;
            bf16x4 o;
#pragma unroll
            for (int r = 0; r < 4; r++) o[r] = __bfloat16_as_short(__float2bfloat16(acc[cg][r]));
            *(bf16x4*)(v_ws + ((size_t)(b * Cc + c)) * Nn + nb) = o;
        }
    }
}

// ---------------- SE gate MLP ----------------
__global__ __launch_bounds__(256) void gate_kernel(
    const float* __restrict__ sum_ws, const float* __restrict__ sumsq_ws,
    const float* __restrict__ W1, const float* __restrict__ W2,
    const float* __restrict__ lamb, float* __restrict__ coef)
{
    int b = blockIdx.x;
    __shared__ float inp[2 * Cc];
    __shared__ float h[32];
    int t = threadIdx.x;
    float s  = sum_ws[b * Cc + t];
    float s2 = sumsq_ws[b * Cc + t];
    float m   = s / Nn;
    float var = (s2 - (float)Nn * m * m) / (float)(Nn - 1);
    inp[t]      = m;
    inp[Cc + t] = sqrtf(fmaxf(var, 0.f));
    __syncthreads();
    if (t < 32) {
        float a = 0.f;
        for (int i = 0; i < 2 * Cc; i++) a += W1[t * (2 * Cc) + i] * inp[i];
        h[t] = fmaxf(a, 0.f);
    }
    __syncthreads();
    float g = 0.f;
#pragma unroll
    for (int r = 0; r < 32; r++) g += W2[t * 32 + r] * h[r];
    float a = 1.f / (1.f + __expf(-g));
    coef[b * Cc + t] = 1.f + lamb[0] * a;
}

// ---------------- flash attention v9: v8 + compile-time acc indexing ----------
// v8 post-mortem: epilogue's acc[mfi][ko+j] with RUNTIME ko (p-dependent) demoted
// the whole acc array to scratch (rule #20): VGPR_Count 52, 6.6 GB scratch traffic,
// 1280 us. v9: identical algorithm; epilogue exchange + store duplicated into
// wave-uniform if(p==0)/else branches with literal 0/8 indices so EVERY acc access
// is compile-time. No other runtime indexing exists (all loops constant-bound).
__global__ __launch_bounds__(512, 2) void attn_kernel(
    const __hip_bfloat16* __restrict__ q_ws, const __hip_bfloat16* __restrict__ k_ws,
    const __hip_bfloat16* __restrict__ v_ws, const float* __restrict__ coef,
    const float* __restrict__ x, const float* __restrict__ gamma_p,
    float* __restrict__ out)
{
    extern __shared__ __hip_bfloat16 smem[];
    __hip_bfloat16* vbuf0 = smem;              // 16384 el (32 KB) each
    __hip_bfloat16* vbuf1 = smem + 16384;
    __hip_bfloat16* kbuf0 = smem + 32768;      // 4096 el (8 KB) each
    __hip_bfloat16* kbuf1 = smem + 36864;      // total 40960 el = 81920 B

    const int b  = blockIdx.x & 7;             // XCD-locality swizzle
    const int m0 = (blockIdx.x >> 3) * 128;
    const int t = threadIdx.x;
    const int w = t >> 6, lane = t & 63, quad = lane >> 4, l15 = lane & 15;
    const int p = w >> 2, pw = w & 3;          // n-parity, m-pair index

    // Q fragments (B-operand) for this wave's 2 m-frags {2pw, 2pw+1}
    const bf16x8 aq0 = *(const bf16x8*)(q_ws + ((size_t)(b * Nn + m0 + (2 * pw)     * 16 + l15)) * Dd + quad * 8);
    const bf16x8 aq1 = *(const bf16x8*)(q_ws + ((size_t)(b * Nn + m0 + (2 * pw + 1) * 16 + l15)) * Dd + quad * 8);

    // V staging: wave w stages frags idx = w*4+j (idx = nchunk*16 + cfrag), linear LDS
    const __hip_bfloat16* vsrc[4];
#pragma unroll
    for (int j = 0; j < 4; j++) {
        int idx = w * 4 + j;
        int ch = idx >> 4, tc = idx & 15;
        vsrc[j] = v_ws + ((size_t)(b * Cc + tc * 16 + l15)) * Nn + ch * 32 + quad * 8;
    }
    // K staging with sigma row permutation (swap bits 2<->3 of l15); slab = 128 n rows
    const int sl15 = (l15 & 3) | ((l15 & 4) << 1) | ((l15 & 8) >> 1);
    const __hip_bfloat16* ksrc = k_ws + ((size_t)(b * Nn + w * 16 + sl15)) * Dd + quad * 8;

    // prestage V(0) + K slab 0; barrier drains DMAs (vmcnt(0) at barrier)
#pragma unroll
    for (int j = 0; j < 4; j++) glds16(vsrc[j], vbuf0 + (w * 4 + j) * 512);
    glds16(ksrc, kbuf0 + w * 512);
    __syncthreads();

    f32x4 acc[2][16];
#pragma unroll
    for (int i = 0; i < 2; i++)
#pragma unroll
        for (int j = 0; j < 16; j++) acc[i][j] = (f32x4){0.f, 0.f, 0.f, 0.f};
    float lsum0 = 0.f, lsum1 = 0.f;

    const int NIT = Nn / 64;

    // prologue: S(0) -> pc (current P regs)
    u32 pc0[2][2], pc1[2][2];
#pragma unroll
    for (int j = 0; j < 2; j++) {
        bf16x8 ak = *(const bf16x8*)(kbuf0 + ((2 * p + j) * 64 + lane) * 8);
        f32x4 s0 = __builtin_amdgcn_mfma_f32_16x16x32_bf16(ak, aq0, (f32x4){0.f,0.f,0.f,0.f}, 0, 0, 0);
        f32x4 s1 = __builtin_amdgcn_mfma_f32_16x16x32_bf16(ak, aq1, (f32x4){0.f,0.f,0.f,0.f}, 0, 0, 0);
        float a0 = __expf(s0[0]), a1 = __expf(s0[1]), a2 = __expf(s0[2]), a3 = __expf(s0[3]);
        lsum0 += (a0 + a1) + (a2 + a3);
        pc0[j][0] = pkbf16(a0, a1); pc0[j][1] = pkbf16(a2, a3);
        float b0 = __expf(s1[0]), b1 = __expf(s1[1]), b2 = __expf(s1[2]), b3 = __expf(s1[3]);
        lsum1 += (b0 + b1) + (b2 + b3);
        pc1[j][0] = pkbf16(b0, b1); pc1[j][1] = pkbf16(b2, b3);
    }

    for (int it = 0; it < NIT; it++) {
        // ---- prefetch next tiles into the other buffers (overlaps whole iter) ----
        if (it + 1 < NIT) {
            __hip_bfloat16* vn = ((it + 1) & 1) ? vbuf1 : vbuf0;
#pragma unroll
            for (int j = 0; j < 4; j++)
                glds16(vsrc[j] + (size_t)(it + 1) * 64, vn + (w * 4 + j) * 512);
        }
        if ((it & 1) == 0 && it + 2 < NIT) {
            int sl = (it >> 1) + 1;
            glds16(ksrc + (size_t)(sl * 128) * Dd, ((sl & 1) ? kbuf1 : kbuf0) + w * 512);
        }

        // ---- B-frags for PV(it) from pc via permlane32_swap (nc = p) ----
        auto g0 = __builtin_amdgcn_permlane32_swap(pc0[0][0], pc0[1][0], false, false);
        auto g1 = __builtin_amdgcn_permlane32_swap(pc0[0][1], pc0[1][1], false, false);
        auto h0 = __builtin_amdgcn_permlane32_swap(pc1[0][0], pc1[1][0], false, false);
        auto h1 = __builtin_amdgcn_permlane32_swap(pc1[0][1], pc1[1][1], false, false);
        union { u32 uw[4]; bf16x8 v; } bp0, bp1;
        bp0.uw[0] = g0[0]; bp0.uw[1] = g1[0]; bp0.uw[2] = g0[1]; bp0.uw[3] = g1[1];
        bp1.uw[0] = h0[0]; bp1.uw[1] = h1[0]; bp1.uw[2] = h0[1]; bp1.uw[3] = h1[1];

        // ---- S(it+1) -> pn; overlaps PV MFMAs below (K slab resident; last iter
        // computes garbage that is never consumed) ----
        u32 pn0[2][2], pn1[2][2];
        const int itn = (it + 1 < NIT) ? it + 1 : it;
        const __hip_bfloat16* kbn = (((itn >> 1) & 1) ? kbuf1 : kbuf0) + (itn & 1) * 2048;
        float nls0 = 0.f, nls1 = 0.f;
#pragma unroll
        for (int j = 0; j < 2; j++) {
            bf16x8 ak = *(const bf16x8*)(kbn + ((2 * p + j) * 64 + lane) * 8);
            f32x4 s0 = __builtin_amdgcn_mfma_f32_16x16x32_bf16(ak, aq0, (f32x4){0.f,0.f,0.f,0.f}, 0, 0, 0);
            f32x4 s1 = __builtin_amdgcn_mfma_f32_16x16x32_bf16(ak, aq1, (f32x4){0.f,0.f,0.f,0.f}, 0, 0, 0);
            float a0 = __expf(s0[0]), a1 = __expf(s0[1]), a2 = __expf(s0[2]), a3 = __expf(s0[3]);
            nls0 += (a0 + a1) + (a2 + a3);
            pn0[j][0] = pkbf16(a0, a1); pn0[j][1] = pkbf16(a2, a3);
            float b0 = __expf(s1[0]), b1 = __expf(s1[1]), b2 = __expf(s1[2]), b3 = __expf(s1[3]);
            nls1 += (b0 + b1) + (b2 + b3);
            pn1[j][0] = pkbf16(b0, b1); pn1[j][1] = pkbf16(b2, b3);
        }
        if (it + 1 < NIT) { lsum0 += nls0; lsum1 += nls1; }

        // ---- O^T += V P^T over this wave's n-half (kc = p) ----
        const __hip_bfloat16* vb = (it & 1) ? vbuf1 : vbuf0;
#pragma unroll
        for (int cf = 0; cf < 16; cf++) {
            bf16x8 av = *(const bf16x8*)(vb + ((p * 16 + cf) * 64 + lane) * 8);
            acc[0][cf] = __builtin_amdgcn_mfma_f32_16x16x32_bf16(av, bp0.v, acc[0][cf], 0, 0, 0);
            acc[1][cf] = __builtin_amdgcn_mfma_f32_16x16x32_bf16(av, bp1.v, acc[1][cf], 0, 0, 0);
        }

        // rotate P regs
#pragma unroll
        for (int j = 0; j < 2; j++)
#pragma unroll
            for (int k = 0; k < 2; k++) { pc0[j][k] = pn0[j][k]; pc1[j][k] = pn1[j][k]; }

        __syncthreads();  // dbuf rotation: all reads of cur buffers done; DMAs drained
    }

    // ---- cross-parity reduction: (w, w^4) hold disjoint-n partials of same output.
    // ALL acc indices compile-time (rule #20): wave-uniform branches on p. ----
    float* lex = (float*)(smem + 32768);   // bytes 65536..69632 over dead kbuf
    lex[w * 128 + lane]      = lsum0;
    lex[w * 128 + 64 + lane] = lsum1;
    f32x4* exv = (f32x4*)smem;             // bytes 0..65520 over dead vbuf
#pragma unroll
    for (int mfi = 0; mfi < 2; mfi++) {
        __syncthreads();
        if (p == 0) {
#pragma unroll
            for (int j = 0; j < 8; j++) exv[(w * 8 + j) * 64 + lane] = acc[mfi][8 + j];
        } else {
#pragma unroll
            for (int j = 0; j < 8; j++) exv[(w * 8 + j) * 64 + lane] = acc[mfi][j];
        }
        __syncthreads();
        if (p == 0) {
#pragma unroll
            for (int j = 0; j < 8; j++) acc[mfi][j] += exv[((w ^ 4) * 8 + j) * 64 + lane];
        } else {
#pragma unroll
            for (int j = 0; j < 8; j++) acc[mfi][8 + j] += exv[((w ^ 4) * 8 + j) * 64 + lane];
        }
        if (mfi == 0) {
            lsum0 += lex[(w ^ 4) * 128 + lane];
            lsum1 += lex[(w ^ 4) * 128 + 64 + lane];
        }
    }

    // ---- epilogue: l[m] reduce over quads (m = l15 is lane-local), then store ----
    lsum0 += __shfl_xor(lsum0, 16); lsum0 += __shfl_xor(lsum0, 32);
    lsum1 += __shfl_xor(lsum1, 16); lsum1 += __shfl_xor(lsum1, 32);
    const float g = gamma_p[0];
    const float inv0 = g / lsum0, inv1 = g / lsum1;

    if (p == 0) {
#pragma unroll
        for (int j = 0; j < 8; j++) {
#pragma unroll
            for (int r = 0; r < 4; r++) {
                int c = j * 16 + quad * 4 + r;
                float cfv = coef[b * Cc + c];
                size_t base = ((size_t)(b * Cc + c)) * Nn + m0 + (2 * pw) * 16 + l15;
                out[base]      = acc[0][j][r] * inv0 + cfv * x[base];
                out[base + 16] = acc[1][j][r] * inv1 + cfv * x[base + 16];
            }
        }
    } else {
#pragma unroll
        for (int j = 0; j < 8; j++) {
#pragma unroll
            for (int r = 0; r < 4; r++) {
                int c = (8 + j) * 16 + quad * 4 + r;
                float cfv = coef[b * Cc + c];
                size_t base = ((size_t)(b * Cc + c)) * Nn + m0 + (2 * pw) * 16 + l15;
                out[base]      = acc[0][8 + j][r] * inv0 + cfv * x[base];
                out[base + 16] = acc[1][8 + j][r] * inv1 + cfv * x[base + 16];
            }
        }
    }
}

extern "C" void kernel_launch(void* const* d_in, const int* in_sizes, int n_in,
                              void* d_out, int out_size, void* d_ws, size_t ws_size,
                              hipStream_t stream) {
    const float* x     = (const float*)d_in[0];
    const float* Wq    = (const float*)d_in[1];
    const float* bq    = (const float*)d_in[2];
    const float* Wk    = (const float*)d_in[3];
    const float* bk    = (const float*)d_in[4];
    const float* Wv    = (const float*)d_in[5];
    const float* bv    = (const float*)d_in[6];
    const float* gamma = (const float*)d_in[7];
    const float* W1    = (const float*)d_in[8];
    const float* W2    = (const float*)d_in[9];
    const float* lamb  = (const float*)d_in[10];
    float* out = (float*)d_out;

    char* ws = (char*)d_ws;
    __hip_bfloat16* q_ws = (__hip_bfloat16*)ws;                       //  2 MB
    __hip_bfloat16* k_ws = (__hip_bfloat16*)(ws + (2u  << 20));       //  2 MB
    __hip_bfloat16* v_ws = (__hip_bfloat16*)(ws + (4u  << 20));       // 16 MB
    __hip_bfloat16* x_t  = (__hip_bfloat16*)(ws + (20u << 20));       // 16 MB
    float* sum_ws   = (float*)(ws + (36u << 20));
    float* sumsq_ws = sum_ws + Bb * Cc;
    float* coef     = sumsq_ws + Bb * Cc;
    __hip_bfloat16* w_bf = (__hip_bfloat16*)(ws + (37u << 20));       // 320 KB

    (void)hipFuncSetAttribute((const void*)attn_kernel,
                              hipFuncAttributeMaxDynamicSharedMemorySize, 81920);

    hipMemsetAsync(sum_ws, 0, 2 * Bb * Cc * sizeof(float), stream);
    wconv_kernel<<<5, 256, 0, stream>>>(Wq, Wk, Wv, w_bf);
    convt_kernel<<<dim3(Nn / 64, Cc / 64, Bb), 256, 0, stream>>>(x, x_t, sum_ws, sumsq_ws);
    proj_kernel<<<dim3(Nn / 64, 5, Bb), 256, 0, stream>>>(x_t, w_bf, bq, bk, bv, q_ws, k_ws, v_ws);
    gate_kernel<<<Bb, 256, 0, stream>>>(sum_ws, sumsq_ws, W1, W2, lamb, coef);
    attn_kernel<<<256, 512, 81920, stream>>>(q_ws, k_ws, v_ws, coef, x, gamma, out);
}

// Round 6
// 235.578 us; speedup vs baseline: 5.8813x; 1.0428x over previous
//
#include <hip/hip_runtime.h>
#include <hip/hip_bf16.h>

#define Bb 8
#define Cc 256
#define Nn 4096
#define Dd 32

typedef short bf16x8 __attribute__((ext_vector_type(8)));
typedef short bf16x4 __attribute__((ext_vector_type(4)));
typedef float f32x4 __attribute__((ext_vector_type(4)));
typedef unsigned int u32;

__device__ __forceinline__ void glds16(const void* g, void* l) {
    __builtin_amdgcn_global_load_lds(
        (const __attribute__((address_space(1))) unsigned int*)g,
        (__attribute__((address_space(3))) unsigned int*)l, 16, 0, 0);
}

// pack two f32 -> one u32 of 2 bf16 (low = a). Compiler fuses to v_cvt_pk_bf16_f32.
__device__ __forceinline__ u32 pkbf16(float a, float b) {
    return ((u32)__bfloat16_as_ushort(__float2bfloat16(b)) << 16) |
           (u32)__bfloat16_as_ushort(__float2bfloat16(a));
}

// ---------------- transpose-convert x -> x_t[b][n][c] bf16, fused stats ----------------
__global__ __launch_bounds__(256) void convt_kernel(
    const float* __restrict__ x, __hip_bfloat16* __restrict__ x_t,
    float* __restrict__ sum_ws, float* __restrict__ sumsq_ws)
{
    __shared__ __hip_bfloat16 tile[64][68];
    const int n0 = blockIdx.x * 64, c0 = blockIdx.y * 64, b = blockIdx.z;
    const int t = threadIdx.x;

#pragma unroll
    for (int i = 0; i < 4; i++) {
        int id = i * 256 + t;
        int row = id >> 4, col4 = id & 15;
        float4 v = *(const float4*)(x + ((size_t)(b * Cc + c0 + row)) * Nn + n0 + col4 * 4);
        bf16x4 bv;
        bv[0] = __bfloat16_as_short(__float2bfloat16(v.x));
        bv[1] = __bfloat16_as_short(__float2bfloat16(v.y));
        bv[2] = __bfloat16_as_short(__float2bfloat16(v.z));
        bv[3] = __bfloat16_as_short(__float2bfloat16(v.w));
        *(bf16x4*)((void*)&tile[row][col4 * 4]) = bv;
        float ls  = v.x + v.y + v.z + v.w;
        float ls2 = v.x * v.x + v.y * v.y + v.z * v.z + v.w * v.w;
        ls  += __shfl_xor(ls, 1, 16);  ls2 += __shfl_xor(ls2, 1, 16);
        ls  += __shfl_xor(ls, 2, 16);  ls2 += __shfl_xor(ls2, 2, 16);
        ls  += __shfl_xor(ls, 4, 16);  ls2 += __shfl_xor(ls2, 4, 16);
        ls  += __shfl_xor(ls, 8, 16);  ls2 += __shfl_xor(ls2, 8, 16);
        if ((t & 15) == 0) {
            atomicAdd(&sum_ws[b * Cc + c0 + row], ls);
            atomicAdd(&sumsq_ws[b * Cc + c0 + row], ls2);
        }
    }
    __syncthreads();
#pragma unroll
    for (int i = 0; i < 2; i++) {
        int id = i * 256 + t;
        int nl = id >> 3, cg = id & 7;
        bf16x8 o;
#pragma unroll
        for (int j = 0; j < 8; j++) o[j] = __bfloat16_as_short(tile[cg * 8 + j][nl]);
        *(bf16x8*)(x_t + ((size_t)(b * Nn + n0 + nl)) * Cc + c0 + cg * 8) = o;
    }
}

// ---------------- W -> bf16 frag-block layout (run once, 5 blocks) ----------------
__global__ __launch_bounds__(256) void wconv_kernel(
    const float* __restrict__ Wq, const float* __restrict__ Wk, const float* __restrict__ Wv,
    __hip_bfloat16* __restrict__ w_bf)
{
    const int ct = blockIdx.x;
    const int t = threadIdx.x;
#pragma unroll
    for (int i = 0; i < 8; i++) {
        int g = i * 256 + t;
        int row = g >> 5, c8 = g & 31;
        int c0 = c8 * 8;
        int grow = ct * 64 + row;
        const float* src;
        if (grow < 32)       src = Wq + (size_t)grow * Cc + c0;
        else if (grow < 64)  src = Wk + (size_t)(grow - 32) * Cc + c0;
        else                 src = Wv + (size_t)(grow - 64) * Cc + c0;
        float4 v0 = *(const float4*)src;
        float4 v1 = *(const float4*)(src + 4);
        bf16x8 o;
        o[0] = __bfloat16_as_short(__float2bfloat16(v0.x));
        o[1] = __bfloat16_as_short(__float2bfloat16(v0.y));
        o[2] = __bfloat16_as_short(__float2bfloat16(v0.z));
        o[3] = __bfloat16_as_short(__float2bfloat16(v0.w));
        o[4] = __bfloat16_as_short(__float2bfloat16(v1.x));
        o[5] = __bfloat16_as_short(__float2bfloat16(v1.y));
        o[6] = __bfloat16_as_short(__float2bfloat16(v1.z));
        o[7] = __bfloat16_as_short(__float2bfloat16(v1.w));
        int kchunk = c0 >> 5, qd = (c0 & 31) >> 3, cg = row >> 4, rl = row & 15;
        *(bf16x8*)(w_bf + ((size_t)ct * 32 + kchunk * 4 + cg) * 512 + (qd * 16 + rl) * 8) = o;
    }
}

// ---------------- MFMA projection ----------------
__global__ __launch_bounds__(256, 2) void proj_kernel(
    const __hip_bfloat16* __restrict__ x_t, const __hip_bfloat16* __restrict__ w_bf,
    const float* __restrict__ bq, const float* __restrict__ bk, const float* __restrict__ bv,
    __hip_bfloat16* __restrict__ q_ws, __hip_bfloat16* __restrict__ k_ws,
    __hip_bfloat16* __restrict__ v_ws)
{
    __shared__ __hip_bfloat16 ldsX[32 * 512];
    __shared__ __hip_bfloat16 ldsW[32 * 512];

    const int n0 = blockIdx.x * 64;
    const int ct = blockIdx.y;
    const int b  = blockIdx.z;
    const int t = threadIdx.x;
    const int w = t >> 6, lane = t & 63, quad = lane >> 4, l15 = lane & 15;

#pragma unroll
    for (int j = 0; j < 8; j++) {
        int idx = w * 8 + j;
        int kchunk = idx >> 2, ngrp = idx & 3;
        glds16(x_t + ((size_t)(b * Nn + n0 + ngrp * 16 + l15)) * Cc + kchunk * 32 + quad * 8,
               ldsX + idx * 512);
        glds16(w_bf + ((size_t)ct * 32 + idx) * 512 + lane * 8, ldsW + idx * 512);
    }
    __syncthreads();

    f32x4 acc[4];
#pragma unroll
    for (int cg = 0; cg < 4; cg++) {
        int gcol = ct * 64 + cg * 16 + l15;
        float bias = (gcol < 32) ? bq[gcol] : (gcol < 64 ? bk[gcol - 32] : bv[gcol - 64]);
        acc[cg] = (f32x4){bias, bias, bias, bias};
    }

#pragma unroll
    for (int kchunk = 0; kchunk < 8; kchunk++) {
        bf16x8 a = *(const bf16x8*)(ldsX + ((kchunk * 4 + w) * 64 + lane) * 8);
#pragma unroll
        for (int cg = 0; cg < 4; cg++) {
            bf16x8 bw = *(const bf16x8*)(ldsW + ((kchunk * 4 + cg) * 64 + lane) * 8);
            acc[cg] = __builtin_amdgcn_mfma_f32_16x16x32_bf16(a, bw, acc[cg], 0, 0, 0);
        }
    }

#pragma unroll
    for (int cg = 0; cg < 4; cg++) {
        int gcol = ct * 64 + cg * 16 + l15;
        int nb = n0 + w * 16 + quad * 4;
        if (gcol < 64) {
            __hip_bfloat16* dst = (gcol < 32) ? q_ws : k_ws;
            int d = gcol & 31;
#pragma unroll
            for (int r = 0; r < 4; r++)
                dst[((size_t)(b * Nn + nb + r)) * Dd + d] = __float2bfloat16(acc[cg][r]);
        } else {
            int c = gcol - 64;
            bf16x4 o;
#pragma unroll
            for (int r = 0; r < 4; r++) o[r] = __bfloat16_as_short(__float2bfloat16(acc[cg][r]));
            *(bf16x4*)(v_ws + ((size_t)(b * Cc + c)) * Nn + nb) = o;
        }
    }
}

// ---------------- SE gate MLP ----------------
__global__ __launch_bounds__(256) void gate_kernel(
    const float* __restrict__ sum_ws, const float* __restrict__ sumsq_ws,
    const float* __restrict__ W1, const float* __restrict__ W2,
    const float* __restrict__ lamb, float* __restrict__ coef)
{
    int b = blockIdx.x;
    __shared__ float inp[2 * Cc];
    __shared__ float h[32];
    int t = threadIdx.x;
    float s  = sum_ws[b * Cc + t];
    float s2 = sumsq_ws[b * Cc + t];
    float m   = s / Nn;
    float var = (s2 - (float)Nn * m * m) / (float)(Nn - 1);
    inp[t]      = m;
    inp[Cc + t] = sqrtf(fmaxf(var, 0.f));
    __syncthreads();
    if (t < 32) {
        float a = 0.f;
        for (int i = 0; i < 2 * Cc; i++) a += W1[t * (2 * Cc) + i] * inp[i];
        h[t] = fmaxf(a, 0.f);
    }
    __syncthreads();
    float g = 0.f;
#pragma unroll
    for (int r = 0; r < 32; r++) g += W2[t * 32 + r] * h[r];
    float a = 1.f / (1.f + __expf(-g));
    coef[b * Cc + t] = 1.f + lamb[0] * a;
}

// ---------------- flash attention v10: v9 + T4 counted-vmcnt barrier, 3-deep bufs ----
// v9 post-mortem: iter = 4275 cyc vs LDS-pipe bound ~2160; __syncthreads lowers to
// s_waitcnt vmcnt(0) -> drains the prefetch DMAs issued THIS iter (2-deep bufs give
// zero slack). v10: V 3-deep (stage it+2), K slabs 3-deep (stage slab+2, >=3 barriers
// ahead); barrier becomes asm{s_waitcnt vmcnt(4); s_barrier} -- in-order vmcnt
// retirement means <=4 outstanding (= this iter's 4 V loads) implies all older DMAs
// retired, so V(it+1)/K needed next iter are complete. Tail iters with no issues use
// vmcnt(0). No lgkm drain needed: every ds_read is consumed by an MFMA before the
// barrier (compiler's dep-waitcnt). Buffer rotation = pointer swaps (rule #20 safe).
// Hazards: V RAW stage@it read@it+2 (forced at end-of-it+1); V WAR dest=V(it-1) buf
// (reads done pre-barrier); K RAW 3 barriers; K WAR slab s-1 last read it-1.
__global__ __launch_bounds__(512, 2) void attn_kernel(
    const __hip_bfloat16* __restrict__ q_ws, const __hip_bfloat16* __restrict__ k_ws,
    const __hip_bfloat16* __restrict__ v_ws, const float* __restrict__ coef,
    const float* __restrict__ x, const float* __restrict__ gamma_p,
    float* __restrict__ out)
{
    extern __shared__ __hip_bfloat16 smem[];
    // V: 3 x 16384 el (32 KB each); K: 3 x 4096 el (8 KB each) = 122880 B total
    __hip_bfloat16 *vcur = smem, *vnext = smem + 16384, *vnn = smem + 32768;
    __hip_bfloat16 *kA = smem + 49152, *kB = smem + 53248, *kC = smem + 57344;

    const int b  = blockIdx.x & 7;             // XCD-locality swizzle
    const int m0 = (blockIdx.x >> 3) * 128;
    const int t = threadIdx.x;
    const int w = t >> 6, lane = t & 63, quad = lane >> 4, l15 = lane & 15;
    const int p = w >> 2, pw = w & 3;          // n-parity, m-pair index

    // Q fragments (B-operand) for this wave's 2 m-frags {2pw, 2pw+1}
    const bf16x8 aq0 = *(const bf16x8*)(q_ws + ((size_t)(b * Nn + m0 + (2 * pw)     * 16 + l15)) * Dd + quad * 8);
    const bf16x8 aq1 = *(const bf16x8*)(q_ws + ((size_t)(b * Nn + m0 + (2 * pw + 1) * 16 + l15)) * Dd + quad * 8);

    // V staging: wave w stages frags idx = w*4+j (idx = nchunk*16 + cfrag), linear LDS
    const __hip_bfloat16* vsrc[4];
#pragma unroll
    for (int j = 0; j < 4; j++) {
        int idx = w * 4 + j;
        int ch = idx >> 4, tc = idx & 15;
        vsrc[j] = v_ws + ((size_t)(b * Cc + tc * 16 + l15)) * Nn + ch * 32 + quad * 8;
    }
    // K staging with sigma row permutation (swap bits 2<->3 of l15); slab = 128 n rows
    const int sl15 = (l15 & 3) | ((l15 & 4) << 1) | ((l15 & 8) >> 1);
    const __hip_bfloat16* ksrc = k_ws + ((size_t)(b * Nn + w * 16 + sl15)) * Dd + quad * 8;

    // prestage V(0), V(1), K slab 0, K slab 1; full drain via __syncthreads
#pragma unroll
    for (int j = 0; j < 4; j++) glds16(vsrc[j], vcur + (w * 4 + j) * 512);
#pragma unroll
    for (int j = 0; j < 4; j++) glds16(vsrc[j] + 64, vnext + (w * 4 + j) * 512);
    glds16(ksrc, kA + w * 512);
    glds16(ksrc + (size_t)128 * Dd, kB + w * 512);
    __syncthreads();

    f32x4 acc[2][16];
#pragma unroll
    for (int i = 0; i < 2; i++)
#pragma unroll
        for (int j = 0; j < 16; j++) acc[i][j] = (f32x4){0.f, 0.f, 0.f, 0.f};
    float lsum0 = 0.f, lsum1 = 0.f;

    const int NIT = Nn / 64;

    // prologue: S(0) -> pc (current P regs) from kA half 0
    u32 pc0[2][2], pc1[2][2];
#pragma unroll
    for (int j = 0; j < 2; j++) {
        bf16x8 ak = *(const bf16x8*)(kA + ((2 * p + j) * 64 + lane) * 8);
        f32x4 s0 = __builtin_amdgcn_mfma_f32_16x16x32_bf16(ak, aq0, (f32x4){0.f,0.f,0.f,0.f}, 0, 0, 0);
        f32x4 s1 = __builtin_amdgcn_mfma_f32_16x16x32_bf16(ak, aq1, (f32x4){0.f,0.f,0.f,0.f}, 0, 0, 0);
        float a0 = __expf(s0[0]), a1 = __expf(s0[1]), a2 = __expf(s0[2]), a3 = __expf(s0[3]);
        lsum0 += (a0 + a1) + (a2 + a3);
        pc0[j][0] = pkbf16(a0, a1); pc0[j][1] = pkbf16(a2, a3);
        float b0 = __expf(s1[0]), b1 = __expf(s1[1]), b2 = __expf(s1[2]), b3 = __expf(s1[3]);
        lsum1 += (b0 + b1) + (b2 + b3);
        pc1[j][0] = pkbf16(b0, b1); pc1[j][1] = pkbf16(b2, b3);
    }

    for (int it = 0; it < NIT; it++) {
        // ---- prefetch: V(it+2) -> vnn; K slab (it/2)+2 -> kC (even iters) ----
        if (it + 2 < NIT) {
#pragma unroll
            for (int j = 0; j < 4; j++)
                glds16(vsrc[j] + (size_t)(it + 2) * 64, vnn + (w * 4 + j) * 512);
        }
        if ((it & 1) == 0 && (it >> 1) + 2 < 32)
            glds16(ksrc + (size_t)(((it >> 1) + 2) * 128) * Dd, kC + w * 512);

        // ---- B-frags for PV(it) from pc via permlane32_swap (nc = p) ----
        auto g0 = __builtin_amdgcn_permlane32_swap(pc0[0][0], pc0[1][0], false, false);
        auto g1 = __builtin_amdgcn_permlane32_swap(pc0[0][1], pc0[1][1], false, false);
        auto h0 = __builtin_amdgcn_permlane32_swap(pc1[0][0], pc1[1][0], false, false);
        auto h1 = __builtin_amdgcn_permlane32_swap(pc1[0][1], pc1[1][1], false, false);
        union { u32 uw[4]; bf16x8 v; } bp0, bp1;
        bp0.uw[0] = g0[0]; bp0.uw[1] = g1[0]; bp0.uw[2] = g0[1]; bp0.uw[3] = g1[1];
        bp1.uw[0] = h0[0]; bp1.uw[1] = h1[0]; bp1.uw[2] = h0[1]; bp1.uw[3] = h1[1];

        // ---- S(it+1) -> pn; overlaps PV below. kA holds slab it>>1, kB the next. ----
        u32 pn0[2][2], pn1[2][2];
        const int itn = (it + 1 < NIT) ? it + 1 : NIT - 1;
        const __hip_bfloat16* kb = (((itn >> 1) > (it >> 1)) ? kB : kA) + (itn & 1) * 2048;
        float nls0 = 0.f, nls1 = 0.f;
#pragma unroll
        for (int j = 0; j < 2; j++) {
            bf16x8 ak = *(const bf16x8*)(kb + ((2 * p + j) * 64 + lane) * 8);
            f32x4 s0 = __builtin_amdgcn_mfma_f32_16x16x32_bf16(ak, aq0, (f32x4){0.f,0.f,0.f,0.f}, 0, 0, 0);
            f32x4 s1 = __builtin_amdgcn_mfma_f32_16x16x32_bf16(ak, aq1, (f32x4){0.f,0.f,0.f,0.f}, 0, 0, 0);
            float a0 = __expf(s0[0]), a1 = __expf(s0[1]), a2 = __expf(s0[2]), a3 = __expf(s0[3]);
            nls0 += (a0 + a1) + (a2 + a3);
            pn0[j][0] = pkbf16(a0, a1); pn0[j][1] = pkbf16(a2, a3);
            float b0 = __expf(s1[0]), b1 = __expf(s1[1]), b2 = __expf(s1[2]), b3 = __expf(s1[3]);
            nls1 += (b0 + b1) + (b2 + b3);
            pn1[j][0] = pkbf16(b0, b1); pn1[j][1] = pkbf16(b2, b3);
        }
        if (it + 1 < NIT) { lsum0 += nls0; lsum1 += nls1; }

        // ---- O^T += V P^T over this wave's n-half (kc = p) ----
#pragma unroll
        for (int cf = 0; cf < 16; cf++) {
            bf16x8 av = *(const bf16x8*)(vcur + ((p * 16 + cf) * 64 + lane) * 8);
            acc[0][cf] = __builtin_amdgcn_mfma_f32_16x16x32_bf16(av, bp0.v, acc[0][cf], 0, 0, 0);
            acc[1][cf] = __builtin_amdgcn_mfma_f32_16x16x32_bf16(av, bp1.v, acc[1][cf], 0, 0, 0);
        }

        // rotate P regs
#pragma unroll
        for (int j = 0; j < 2; j++)
#pragma unroll
            for (int k = 0; k < 2; k++) { pc0[j][k] = pn0[j][k]; pc1[j][k] = pn1[j][k]; }

        // rotate buffers (register pointer swaps)
        { __hip_bfloat16* vt = vcur; vcur = vnext; vnext = vnn; vnn = vt; }
        if (it & 1) { __hip_bfloat16* kt = kA; kA = kB; kB = kC; kC = kt; }

        // ---- T4 barrier: counted vmcnt keeps this iter's prefetch in flight ----
        if (it + 2 < NIT)
            asm volatile("s_waitcnt vmcnt(4)\n\ts_barrier" ::: "memory");
        else
            asm volatile("s_waitcnt vmcnt(0)\n\ts_barrier" ::: "memory");
    }

    // ---- cross-parity reduction: (w, w^4) hold disjoint-n partials of same output.
    // ALL acc indices compile-time (rule #20): wave-uniform branches on p. ----
    float* lex = (float*)(smem + 32768);   // bytes 65536..69632 over dead LDS
    lex[w * 128 + lane]      = lsum0;
    lex[w * 128 + 64 + lane] = lsum1;
    f32x4* exv = (f32x4*)smem;             // bytes 0..65536 over dead LDS
#pragma unroll
    for (int mfi = 0; mfi < 2; mfi++) {
        __syncthreads();
        if (p == 0) {
#pragma unroll
            for (int j = 0; j < 8; j++) exv[(w * 8 + j) * 64 + lane] = acc[mfi][8 + j];
        } else {
#pragma unroll
            for (int j = 0; j < 8; j++) exv[(w * 8 + j) * 64 + lane] = acc[mfi][j];
        }
        __syncthreads();
        if (p == 0) {
#pragma unroll
            for (int j = 0; j < 8; j++) acc[mfi][j] += exv[((w ^ 4) * 8 + j) * 64 + lane];
        } else {
#pragma unroll
            for (int j = 0; j < 8; j++) acc[mfi][8 + j] += exv[((w ^ 4) * 8 + j) * 64 + lane];
        }
        if (mfi == 0) {
            lsum0 += lex[(w ^ 4) * 128 + lane];
            lsum1 += lex[(w ^ 4) * 128 + 64 + lane];
        }
    }

    // ---- epilogue: l[m] reduce over quads (m = l15 is lane-local), then store ----
    lsum0 += __shfl_xor(lsum0, 16); lsum0 += __shfl_xor(lsum0, 32);
    lsum1 += __shfl_xor(lsum1, 16); lsum1 += __shfl_xor(lsum1, 32);
    const float g = gamma_p[0];
    const float inv0 = g / lsum0, inv1 = g / lsum1;

    if (p == 0) {
#pragma unroll
        for (int j = 0; j < 8; j++) {
#pragma unroll
            for (int r = 0; r < 4; r++) {
                int c = j * 16 + quad * 4 + r;
                float cfv = coef[b * Cc + c];
                size_t base = ((size_t)(b * Cc + c)) * Nn + m0 + (2 * pw) * 16 + l15;
                out[base]      = acc[0][j][r] * inv0 + cfv * x[base];
                out[base + 16] = acc[1][j][r] * inv1 + cfv * x[base + 16];
            }
        }
    } else {
#pragma unroll
        for (int j = 0; j < 8; j++) {
#pragma unroll
            for (int r = 0; r < 4; r++) {
                int c = (8 + j) * 16 + quad * 4 + r;
                float cfv = coef[b * Cc + c];
                size_t base = ((size_t)(b * Cc + c)) * Nn + m0 + (2 * pw) * 16 + l15;
                out[base]      = acc[0][8 + j][r] * inv0 + cfv * x[base];
                out[base + 16] = acc[1][8 + j][r] * inv1 + cfv * x[base + 16];
            }
        }
    }
}

extern "C" void kernel_launch(void* const* d_in, const int* in_sizes, int n_in,
                              void* d_out, int out_size, void* d_ws, size_t ws_size,
                              hipStream_t stream) {
    const float* x     = (const float*)d_in[0];
    const float* Wq    = (const float*)d_in[1];
    const float* bq    = (const float*)d_in[2];
    const float* Wk    = (const float*)d_in[3];
    const float* bk    = (const float*)d_in[4];
    const float* Wv    = (const float*)d_in[5];
    const float* bv    = (const float*)d_in[6];
    const float* gamma = (const float*)d_in[7];
    const float* W1    = (const float*)d_in[8];
    const float* W2    = (const float*)d_in[9];
    const float* lamb  = (const float*)d_in[10];
    float* out = (float*)d_out;

    char* ws = (char*)d_ws;
    __hip_bfloat16* q_ws = (__hip_bfloat16*)ws;                       //  2 MB
    __hip_bfloat16* k_ws = (__hip_bfloat16*)(ws + (2u  << 20));       //  2 MB
    __hip_bfloat16* v_ws = (__hip_bfloat16*)(ws + (4u  << 20));       // 16 MB
    __hip_bfloat16* x_t  = (__hip_bfloat16*)(ws + (20u << 20));       // 16 MB
    float* sum_ws   = (float*)(ws + (36u << 20));
    float* sumsq_ws = sum_ws + Bb * Cc;
    float* coef     = sumsq_ws + Bb * Cc;
    __hip_bfloat16* w_bf = (__hip_bfloat16*)(ws + (37u << 20));       // 320 KB

    (void)hipFuncSetAttribute((const void*)attn_kernel,
                              hipFuncAttributeMaxDynamicSharedMemorySize, 122880);

    hipMemsetAsync(sum_ws, 0, 2 * Bb * Cc * sizeof(float), stream);
    wconv_kernel<<<5, 256, 0, stream>>>(Wq, Wk, Wv, w_bf);
    convt_kernel<<<dim3(Nn / 64, Cc / 64, Bb), 256, 0, stream>>>(x, x_t, sum_ws, sumsq_ws);
    proj_kernel<<<dim3(Nn / 64, 5, Bb), 256, 0, stream>>>(x_t, w_bf, bq, bk, bv, q_ws, k_ws, v_ws);
    gate_kernel<<<Bb, 256, 0, stream>>>(sum_ws, sumsq_ws, W1, W2, lamb, coef);
    attn_kernel<<<256, 512, 122880, stream>>>(q_ws, k_ws, v_ws, coef, x, gamma, out);
}

// Round 7
// 228.299 us; speedup vs baseline: 6.0688x; 1.0319x over previous
//
#include <hip/hip_runtime.h>
#include <hip/hip_bf16.h>

#define Bb 8
#define Cc 256
#define Nn 4096
#define Dd 32

typedef short bf16x8 __attribute__((ext_vector_type(8)));
typedef short bf16x4 __attribute__((ext_vector_type(4)));
typedef float f32x4 __attribute__((ext_vector_type(4)));
typedef unsigned int u32;

__device__ __forceinline__ void glds16(const void* g, void* l) {
    __builtin_amdgcn_global_load_lds(
        (const __attribute__((address_space(1))) unsigned int*)g,
        (__attribute__((address_space(3))) unsigned int*)l, 16, 0, 0);
}

// pack two f32 -> one u32 of 2 bf16 (low = a). Compiler fuses to v_cvt_pk_bf16_f32.
__device__ __forceinline__ u32 pkbf16(float a, float b) {
    return ((u32)__bfloat16_as_ushort(__float2bfloat16(b)) << 16) |
           (u32)__bfloat16_as_ushort(__float2bfloat16(a));
}

// ---------------- transpose-convert x -> x_t[b][n][c] bf16, fused stats ----------------
__global__ __launch_bounds__(256) void convt_kernel(
    const float* __restrict__ x, __hip_bfloat16* __restrict__ x_t,
    float* __restrict__ sum_ws, float* __restrict__ sumsq_ws)
{
    __shared__ __hip_bfloat16 tile[64][68];
    const int n0 = blockIdx.x * 64, c0 = blockIdx.y * 64, b = blockIdx.z;
    const int t = threadIdx.x;

#pragma unroll
    for (int i = 0; i < 4; i++) {
        int id = i * 256 + t;
        int row = id >> 4, col4 = id & 15;
        float4 v = *(const float4*)(x + ((size_t)(b * Cc + c0 + row)) * Nn + n0 + col4 * 4);
        bf16x4 bv;
        bv[0] = __bfloat16_as_short(__float2bfloat16(v.x));
        bv[1] = __bfloat16_as_short(__float2bfloat16(v.y));
        bv[2] = __bfloat16_as_short(__float2bfloat16(v.z));
        bv[3] = __bfloat16_as_short(__float2bfloat16(v.w));
        *(bf16x4*)((void*)&tile[row][col4 * 4]) = bv;
        float ls  = v.x + v.y + v.z + v.w;
        float ls2 = v.x * v.x + v.y * v.y + v.z * v.z + v.w * v.w;
        ls  += __shfl_xor(ls, 1, 16);  ls2 += __shfl_xor(ls2, 1, 16);
        ls  += __shfl_xor(ls, 2, 16);  ls2 += __shfl_xor(ls2, 2, 16);
        ls  += __shfl_xor(ls, 4, 16);  ls2 += __shfl_xor(ls2, 4, 16);
        ls  += __shfl_xor(ls, 8, 16);  ls2 += __shfl_xor(ls2, 8, 16);
        if ((t & 15) == 0) {
            atomicAdd(&sum_ws[b * Cc + c0 + row], ls);
            atomicAdd(&sumsq_ws[b * Cc + c0 + row], ls2);
        }
    }
    __syncthreads();
#pragma unroll
    for (int i = 0; i < 2; i++) {
        int id = i * 256 + t;
        int nl = id >> 3, cg = id & 7;
        bf16x8 o;
#pragma unroll
        for (int j = 0; j < 8; j++) o[j] = __bfloat16_as_short(tile[cg * 8 + j][nl]);
        *(bf16x8*)(x_t + ((size_t)(b * Nn + n0 + nl)) * Cc + c0 + cg * 8) = o;
    }
}

// ---------------- W -> bf16 frag-block layout (run once, 5 blocks) ----------------
__global__ __launch_bounds__(256) void wconv_kernel(
    const float* __restrict__ Wq, const float* __restrict__ Wk, const float* __restrict__ Wv,
    __hip_bfloat16* __restrict__ w_bf)
{
    const int ct = blockIdx.x;
    const int t = threadIdx.x;
#pragma unroll
    for (int i = 0; i < 8; i++) {
        int g = i * 256 + t;
        int row = g >> 5, c8 = g & 31;
        int c0 = c8 * 8;
        int grow = ct * 64 + row;
        const float* src;
        if (grow < 32)       src = Wq + (size_t)grow * Cc + c0;
        else if (grow < 64)  src = Wk + (size_t)(grow - 32) * Cc + c0;
        else                 src = Wv + (size_t)(grow - 64) * Cc + c0;
        float4 v0 = *(const float4*)src;
        float4 v1 = *(const float4*)(src + 4);
        bf16x8 o;
        o[0] = __bfloat16_as_short(__float2bfloat16(v0.x));
        o[1] = __bfloat16_as_short(__float2bfloat16(v0.y));
        o[2] = __bfloat16_as_short(__float2bfloat16(v0.z));
        o[3] = __bfloat16_as_short(__float2bfloat16(v0.w));
        o[4] = __bfloat16_as_short(__float2bfloat16(v1.x));
        o[5] = __bfloat16_as_short(__float2bfloat16(v1.y));
        o[6] = __bfloat16_as_short(__float2bfloat16(v1.z));
        o[7] = __bfloat16_as_short(__float2bfloat16(v1.w));
        int kchunk = c0 >> 5, qd = (c0 & 31) >> 3, cg = row >> 4, rl = row & 15;
        *(bf16x8*)(w_bf + ((size_t)ct * 32 + kchunk * 4 + cg) * 512 + (qd * 16 + rl) * 8) = o;
    }
}

// ---------------- MFMA projection v11: x_t staged ONCE, ct loop in-block ----------
// v10 analysis: proj's grid.y=5 re-read x_t 5x (~160 MB of re-fetch) and re-staged
// X per ct. v11: one block per (n0, b); stage X once + W(0); loop ct=0..4 with
// single-buffered ldsW (barrier -> restage -> barrier; hidden by 2 blocks/CU at
// 64 KB LDS). W (320 KB) is L2-resident after first touch. MFMA core + store
// logic byte-identical to the verified v10 proj.
__global__ __launch_bounds__(256, 2) void proj_kernel(
    const __hip_bfloat16* __restrict__ x_t, const __hip_bfloat16* __restrict__ w_bf,
    const float* __restrict__ bq, const float* __restrict__ bk, const float* __restrict__ bv,
    __hip_bfloat16* __restrict__ q_ws, __hip_bfloat16* __restrict__ k_ws,
    __hip_bfloat16* __restrict__ v_ws)
{
    __shared__ __hip_bfloat16 ldsX[32 * 512];
    __shared__ __hip_bfloat16 ldsW[32 * 512];

    const int n0 = blockIdx.x * 64;
    const int b  = blockIdx.y;
    const int t = threadIdx.x;
    const int w = t >> 6, lane = t & 63, quad = lane >> 4, l15 = lane & 15;

    // stage X (once) + W(ct=0)
#pragma unroll
    for (int j = 0; j < 8; j++) {
        int idx = w * 8 + j;
        int kchunk = idx >> 2, ngrp = idx & 3;
        glds16(x_t + ((size_t)(b * Nn + n0 + ngrp * 16 + l15)) * Cc + kchunk * 32 + quad * 8,
               ldsX + idx * 512);
        glds16(w_bf + (size_t)idx * 512 + lane * 8, ldsW + idx * 512);
    }
    __syncthreads();

    for (int ct = 0; ct < 5; ct++) {
        f32x4 acc[4];
#pragma unroll
        for (int cg = 0; cg < 4; cg++) {
            int gcol = ct * 64 + cg * 16 + l15;
            float bias = (gcol < 32) ? bq[gcol] : (gcol < 64 ? bk[gcol - 32] : bv[gcol - 64]);
            acc[cg] = (f32x4){bias, bias, bias, bias};
        }

#pragma unroll
        for (int kchunk = 0; kchunk < 8; kchunk++) {
            bf16x8 a = *(const bf16x8*)(ldsX + ((kchunk * 4 + w) * 64 + lane) * 8);
#pragma unroll
            for (int cg = 0; cg < 4; cg++) {
                bf16x8 bw = *(const bf16x8*)(ldsW + ((kchunk * 4 + cg) * 64 + lane) * 8);
                acc[cg] = __builtin_amdgcn_mfma_f32_16x16x32_bf16(a, bw, acc[cg], 0, 0, 0);
            }
        }

#pragma unroll
        for (int cg = 0; cg < 4; cg++) {
            int gcol = ct * 64 + cg * 16 + l15;
            int nb = n0 + w * 16 + quad * 4;
            if (gcol < 64) {
                __hip_bfloat16* dst = (gcol < 32) ? q_ws : k_ws;
                int d = gcol & 31;
#pragma unroll
                for (int r = 0; r < 4; r++)
                    dst[((size_t)(b * Nn + nb + r)) * Dd + d] = __float2bfloat16(acc[cg][r]);
            } else {
                int c = gcol - 64;
                bf16x4 o;
#pragma unroll
                for (int r = 0; r < 4; r++) o[r] = __bfloat16_as_short(__float2bfloat16(acc[cg][r]));
                *(bf16x4*)(v_ws + ((size_t)(b * Cc + c)) * Nn + nb) = o;
            }
        }

        if (ct < 4) {
            __syncthreads();   // all waves done reading ldsW(ct)
#pragma unroll
            for (int j = 0; j < 8; j++) {
                int idx = w * 8 + j;
                glds16(w_bf + ((size_t)(ct + 1) * 32 + idx) * 512 + lane * 8, ldsW + idx * 512);
            }
            __syncthreads();   // drain DMAs (vmcnt(0) at barrier)
        }
    }
}

// ---------------- SE gate MLP ----------------
__global__ __launch_bounds__(256) void gate_kernel(
    const float* __restrict__ sum_ws, const float* __restrict__ sumsq_ws,
    const float* __restrict__ W1, const float* __restrict__ W2,
    const float* __restrict__ lamb, float* __restrict__ coef)
{
    int b = blockIdx.x;
    __shared__ float inp[2 * Cc];
    __shared__ float h[32];
    int t = threadIdx.x;
    float s  = sum_ws[b * Cc + t];
    float s2 = sumsq_ws[b * Cc + t];
    float m   = s / Nn;
    float var = (s2 - (float)Nn * m * m) / (float)(Nn - 1);
    inp[t]      = m;
    inp[Cc + t] = sqrtf(fmaxf(var, 0.f));
    __syncthreads();
    if (t < 32) {
        float a = 0.f;
        for (int i = 0; i < 2 * Cc; i++) a += W1[t * (2 * Cc) + i] * inp[i];
        h[t] = fmaxf(a, 0.f);
    }
    __syncthreads();
    float g = 0.f;
#pragma unroll
    for (int r = 0; r < 32; r++) g += W2[t * 32 + r] * h[r];
    float a = 1.f / (1.f + __expf(-g));
    coef[b * Cc + t] = 1.f + lamb[0] * a;
}

// ---------------- flash attention v10 (unchanged, verified): T4 counted-vmcnt ----
__global__ __launch_bounds__(512, 2) void attn_kernel(
    const __hip_bfloat16* __restrict__ q_ws, const __hip_bfloat16* __restrict__ k_ws,
    const __hip_bfloat16* __restrict__ v_ws, const float* __restrict__ coef,
    const float* __restrict__ x, const float* __restrict__ gamma_p,
    float* __restrict__ out)
{
    extern __shared__ __hip_bfloat16 smem[];
    // V: 3 x 16384 el (32 KB each); K: 3 x 4096 el (8 KB each) = 122880 B total
    __hip_bfloat16 *vcur = smem, *vnext = smem + 16384, *vnn = smem + 32768;
    __hip_bfloat16 *kA = smem + 49152, *kB = smem + 53248, *kC = smem + 57344;

    const int b  = blockIdx.x & 7;             // XCD-locality swizzle
    const int m0 = (blockIdx.x >> 3) * 128;
    const int t = threadIdx.x;
    const int w = t >> 6, lane = t & 63, quad = lane >> 4, l15 = lane & 15;
    const int p = w >> 2, pw = w & 3;          // n-parity, m-pair index

    // Q fragments (B-operand) for this wave's 2 m-frags {2pw, 2pw+1}
    const bf16x8 aq0 = *(const bf16x8*)(q_ws + ((size_t)(b * Nn + m0 + (2 * pw)     * 16 + l15)) * Dd + quad * 8);
    const bf16x8 aq1 = *(const bf16x8*)(q_ws + ((size_t)(b * Nn + m0 + (2 * pw + 1) * 16 + l15)) * Dd + quad * 8);

    // V staging: wave w stages frags idx = w*4+j (idx = nchunk*16 + cfrag), linear LDS
    const __hip_bfloat16* vsrc[4];
#pragma unroll
    for (int j = 0; j < 4; j++) {
        int idx = w * 4 + j;
        int ch = idx >> 4, tc = idx & 15;
        vsrc[j] = v_ws + ((size_t)(b * Cc + tc * 16 + l15)) * Nn + ch * 32 + quad * 8;
    }
    // K staging with sigma row permutation (swap bits 2<->3 of l15); slab = 128 n rows
    const int sl15 = (l15 & 3) | ((l15 & 4) << 1) | ((l15 & 8) >> 1);
    const __hip_bfloat16* ksrc = k_ws + ((size_t)(b * Nn + w * 16 + sl15)) * Dd + quad * 8;

    // prestage V(0), V(1), K slab 0, K slab 1; full drain via __syncthreads
#pragma unroll
    for (int j = 0; j < 4; j++) glds16(vsrc[j], vcur + (w * 4 + j) * 512);
#pragma unroll
    for (int j = 0; j < 4; j++) glds16(vsrc[j] + 64, vnext + (w * 4 + j) * 512);
    glds16(ksrc, kA + w * 512);
    glds16(ksrc + (size_t)128 * Dd, kB + w * 512);
    __syncthreads();

    f32x4 acc[2][16];
#pragma unroll
    for (int i = 0; i < 2; i++)
#pragma unroll
        for (int j = 0; j < 16; j++) acc[i][j] = (f32x4){0.f, 0.f, 0.f, 0.f};
    float lsum0 = 0.f, lsum1 = 0.f;

    const int NIT = Nn / 64;

    // prologue: S(0) -> pc (current P regs) from kA half 0
    u32 pc0[2][2], pc1[2][2];
#pragma unroll
    for (int j = 0; j < 2; j++) {
        bf16x8 ak = *(const bf16x8*)(kA + ((2 * p + j) * 64 + lane) * 8);
        f32x4 s0 = __builtin_amdgcn_mfma_f32_16x16x32_bf16(ak, aq0, (f32x4){0.f,0.f,0.f,0.f}, 0, 0, 0);
        f32x4 s1 = __builtin_amdgcn_mfma_f32_16x16x32_bf16(ak, aq1, (f32x4){0.f,0.f,0.f,0.f}, 0, 0, 0);
        float a0 = __expf(s0[0]), a1 = __expf(s0[1]), a2 = __expf(s0[2]), a3 = __expf(s0[3]);
        lsum0 += (a0 + a1) + (a2 + a3);
        pc0[j][0] = pkbf16(a0, a1); pc0[j][1] = pkbf16(a2, a3);
        float b0 = __expf(s1[0]), b1 = __expf(s1[1]), b2 = __expf(s1[2]), b3 = __expf(s1[3]);
        lsum1 += (b0 + b1) + (b2 + b3);
        pc1[j][0] = pkbf16(b0, b1); pc1[j][1] = pkbf16(b2, b3);
    }

    for (int it = 0; it < NIT; it++) {
        // ---- prefetch: V(it+2) -> vnn; K slab (it/2)+2 -> kC (even iters) ----
        if (it + 2 < NIT) {
#pragma unroll
            for (int j = 0; j < 4; j++)
                glds16(vsrc[j] + (size_t)(it + 2) * 64, vnn + (w * 4 + j) * 512);
        }
        if ((it & 1) == 0 && (it >> 1) + 2 < 32)
            glds16(ksrc + (size_t)(((it >> 1) + 2) * 128) * Dd, kC + w * 512);

        // ---- B-frags for PV(it) from pc via permlane32_swap (nc = p) ----
        auto g0 = __builtin_amdgcn_permlane32_swap(pc0[0][0], pc0[1][0], false, false);
        auto g1 = __builtin_amdgcn_permlane32_swap(pc0[0][1], pc0[1][1], false, false);
        auto h0 = __builtin_amdgcn_permlane32_swap(pc1[0][0], pc1[1][0], false, false);
        auto h1 = __builtin_amdgcn_permlane32_swap(pc1[0][1], pc1[1][1], false, false);
        union { u32 uw[4]; bf16x8 v; } bp0, bp1;
        bp0.uw[0] = g0[0]; bp0.uw[1] = g1[0]; bp0.uw[2] = g0[1]; bp0.uw[3] = g1[1];
        bp1.uw[0] = h0[0]; bp1.uw[1] = h1[0]; bp1.uw[2] = h0[1]; bp1.uw[3] = h1[1];

        // ---- S(it+1) -> pn; overlaps PV below. kA holds slab it>>1, kB the next. ----
        u32 pn0[2][2], pn1[2][2];
        const int itn = (it + 1 < NIT) ? it + 1 : NIT - 1;
        const __hip_bfloat16* kb = (((itn >> 1) > (it >> 1)) ? kB : kA) + (itn & 1) * 2048;
        float nls0 = 0.f, nls1 = 0.f;
#pragma unroll
        for (int j = 0; j < 2; j++) {
            bf16x8 ak = *(const bf16x8*)(kb + ((2 * p + j) * 64 + lane) * 8);
            f32x4 s0 = __builtin_amdgcn_mfma_f32_16x16x32_bf16(ak, aq0, (f32x4){0.f,0.f,0.f,0.f}, 0, 0, 0);
            f32x4 s1 = __builtin_amdgcn_mfma_f32_16x16x32_bf16(ak, aq1, (f32x4){0.f,0.f,0.f,0.f}, 0, 0, 0);
            float a0 = __expf(s0[0]), a1 = __expf(s0[1]), a2 = __expf(s0[2]), a3 = __expf(s0[3]);
            nls0 += (a0 + a1) + (a2 + a3);
            pn0[j][0] = pkbf16(a0, a1); pn0[j][1] = pkbf16(a2, a3);
            float b0 = __expf(s1[0]), b1 = __expf(s1[1]), b2 = __expf(s1[2]), b3 = __expf(s1[3]);
            nls1 += (b0 + b1) + (b2 + b3);
            pn1[j][0] = pkbf16(b0, b1); pn1[j][1] = pkbf16(b2, b3);
        }
        if (it + 1 < NIT) { lsum0 += nls0; lsum1 += nls1; }

        // ---- O^T += V P^T over this wave's n-half (kc = p) ----
#pragma unroll
        for (int cf = 0; cf < 16; cf++) {
            bf16x8 av = *(const bf16x8*)(vcur + ((p * 16 + cf) * 64 + lane) * 8);
            acc[0][cf] = __builtin_amdgcn_mfma_f32_16x16x32_bf16(av, bp0.v, acc[0][cf], 0, 0, 0);
            acc[1][cf] = __builtin_amdgcn_mfma_f32_16x16x32_bf16(av, bp1.v, acc[1][cf], 0, 0, 0);
        }

        // rotate P regs
#pragma unroll
        for (int j = 0; j < 2; j++)
#pragma unroll
            for (int k = 0; k < 2; k++) { pc0[j][k] = pn0[j][k]; pc1[j][k] = pn1[j][k]; }

        // rotate buffers (register pointer swaps)
        { __hip_bfloat16* vt = vcur; vcur = vnext; vnext = vnn; vnn = vt; }
        if (it & 1) { __hip_bfloat16* kt = kA; kA = kB; kB = kC; kC = kt; }

        // ---- T4 barrier: counted vmcnt keeps this iter's prefetch in flight ----
        if (it + 2 < NIT)
            asm volatile("s_waitcnt vmcnt(4)\n\ts_barrier" ::: "memory");
        else
            asm volatile("s_waitcnt vmcnt(0)\n\ts_barrier" ::: "memory");
    }

    // ---- cross-parity reduction: (w, w^4) hold disjoint-n partials of same output.
    // ALL acc indices compile-time (rule #20): wave-uniform branches on p. ----
    float* lex = (float*)(smem + 32768);   // bytes 65536..69632 over dead LDS
    lex[w * 128 + lane]      = lsum0;
    lex[w * 128 + 64 + lane] = lsum1;
    f32x4* exv = (f32x4*)smem;             // bytes 0..65536 over dead LDS
#pragma unroll
    for (int mfi = 0; mfi < 2; mfi++) {
        __syncthreads();
        if (p == 0) {
#pragma unroll
            for (int j = 0; j < 8; j++) exv[(w * 8 + j) * 64 + lane] = acc[mfi][8 + j];
        } else {
#pragma unroll
            for (int j = 0; j < 8; j++) exv[(w * 8 + j) * 64 + lane] = acc[mfi][j];
        }
        __syncthreads();
        if (p == 0) {
#pragma unroll
            for (int j = 0; j < 8; j++) acc[mfi][j] += exv[((w ^ 4) * 8 + j) * 64 + lane];
        } else {
#pragma unroll
            for (int j = 0; j < 8; j++) acc[mfi][8 + j] += exv[((w ^ 4) * 8 + j) * 64 + lane];
        }
        if (mfi == 0) {
            lsum0 += lex[(w ^ 4) * 128 + lane];
            lsum1 += lex[(w ^ 4) * 128 + 64 + lane];
        }
    }

    // ---- epilogue: l[m] reduce over quads (m = l15 is lane-local), then store ----
    lsum0 += __shfl_xor(lsum0, 16); lsum0 += __shfl_xor(lsum0, 32);
    lsum1 += __shfl_xor(lsum1, 16); lsum1 += __shfl_xor(lsum1, 32);
    const float g = gamma_p[0];
    const float inv0 = g / lsum0, inv1 = g / lsum1;

    if (p == 0) {
#pragma unroll
        for (int j = 0; j < 8; j++) {
#pragma unroll
            for (int r = 0; r < 4; r++) {
                int c = j * 16 + quad * 4 + r;
                float cfv = coef[b * Cc + c];
                size_t base = ((size_t)(b * Cc + c)) * Nn + m0 + (2 * pw) * 16 + l15;
                out[base]      = acc[0][j][r] * inv0 + cfv * x[base];
                out[base + 16] = acc[1][j][r] * inv1 + cfv * x[base + 16];
            }
        }
    } else {
#pragma unroll
        for (int j = 0; j < 8; j++) {
#pragma unroll
            for (int r = 0; r < 4; r++) {
                int c = (8 + j) * 16 + quad * 4 + r;
                float cfv = coef[b * Cc + c];
                size_t base = ((size_t)(b * Cc + c)) * Nn + m0 + (2 * pw) * 16 + l15;
                out[base]      = acc[0][8 + j][r] * inv0 + cfv * x[base];
                out[base + 16] = acc[1][8 + j][r] * inv1 + cfv * x[base + 16];
            }
        }
    }
}

extern "C" void kernel_launch(void* const* d_in, const int* in_sizes, int n_in,
                              void* d_out, int out_size, void* d_ws, size_t ws_size,
                              hipStream_t stream) {
    const float* x     = (const float*)d_in[0];
    const float* Wq    = (const float*)d_in[1];
    const float* bq    = (const float*)d_in[2];
    const float* Wk    = (const float*)d_in[3];
    const float* bk    = (const float*)d_in[4];
    const float* Wv    = (const float*)d_in[5];
    const float* bv    = (const float*)d_in[6];
    const float* gamma = (const float*)d_in[7];
    const float* W1    = (const float*)d_in[8];
    const float* W2    = (const float*)d_in[9];
    const float* lamb  = (const float*)d_in[10];
    float* out = (float*)d_out;

    char* ws = (char*)d_ws;
    __hip_bfloat16* q_ws = (__hip_bfloat16*)ws;                       //  2 MB
    __hip_bfloat16* k_ws = (__hip_bfloat16*)(ws + (2u  << 20));       //  2 MB
    __hip_bfloat16* v_ws = (__hip_bfloat16*)(ws + (4u  << 20));       // 16 MB
    __hip_bfloat16* x_t  = (__hip_bfloat16*)(ws + (20u << 20));       // 16 MB
    float* sum_ws   = (float*)(ws + (36u << 20));
    float* sumsq_ws = sum_ws + Bb * Cc;
    float* coef     = sumsq_ws + Bb * Cc;
    __hip_bfloat16* w_bf = (__hip_bfloat16*)(ws + (37u << 20));       // 320 KB

    (void)hipFuncSetAttribute((const void*)attn_kernel,
                              hipFuncAttributeMaxDynamicSharedMemorySize, 122880);

    hipMemsetAsync(sum_ws, 0, 2 * Bb * Cc * sizeof(float), stream);
    wconv_kernel<<<5, 256, 0, stream>>>(Wq, Wk, Wv, w_bf);
    convt_kernel<<<dim3(Nn / 64, Cc / 64, Bb), 256, 0, stream>>>(x, x_t, sum_ws, sumsq_ws);
    proj_kernel<<<dim3(Nn / 64, Bb), 256, 0, stream>>>(x_t, w_bf, bq, bk, bv, q_ws, k_ws, v_ws);
    gate_kernel<<<Bb, 256, 0, stream>>>(sum_ws, sumsq_ws, W1, W2, lamb, coef);
    attn_kernel<<<256, 512, 122880, stream>>>(q_ws, k_ws, v_ws, coef, x, gamma, out);
}

// Round 8
// 221.471 us; speedup vs baseline: 6.2559x; 1.0308x over previous
//
#include <hip/hip_runtime.h>
#include <hip/hip_bf16.h>

#define Bb 8
#define Cc 256
#define Nn 4096
#define Dd 32

typedef short bf16x8 __attribute__((ext_vector_type(8)));
typedef short bf16x4 __attribute__((ext_vector_type(4)));
typedef float f32x4 __attribute__((ext_vector_type(4)));
typedef unsigned int u32;

__device__ __forceinline__ void glds16(const void* g, void* l) {
    __builtin_amdgcn_global_load_lds(
        (const __attribute__((address_space(1))) unsigned int*)g,
        (__attribute__((address_space(3))) unsigned int*)l, 16, 0, 0);
}

// pack two f32 -> one u32 of 2 bf16 (low = a). Compiler fuses to v_cvt_pk_bf16_f32.
__device__ __forceinline__ u32 pkbf16(float a, float b) {
    return ((u32)__bfloat16_as_ushort(__float2bfloat16(b)) << 16) |
           (u32)__bfloat16_as_ushort(__float2bfloat16(a));
}

// ---------------- W -> bf16 frag-block layout + zero stats (runs first in stream) ----
__global__ __launch_bounds__(256) void wconv_kernel(
    const float* __restrict__ Wq, const float* __restrict__ Wk, const float* __restrict__ Wv,
    __hip_bfloat16* __restrict__ w_bf, float* __restrict__ stats /* 2*Bb*Cc floats */)
{
    const int ct = blockIdx.x;
    const int t = threadIdx.x;
    // fold the old hipMemsetAsync into this (first) kernel: grid-stride zero
    for (int k = ct * 256 + t; k < 2 * Bb * Cc; k += 5 * 256) stats[k] = 0.f;
#pragma unroll
    for (int i = 0; i < 8; i++) {
        int g = i * 256 + t;
        int row = g >> 5, c8 = g & 31;
        int c0 = c8 * 8;
        int grow = ct * 64 + row;
        const float* src;
        if (grow < 32)       src = Wq + (size_t)grow * Cc + c0;
        else if (grow < 64)  src = Wk + (size_t)(grow - 32) * Cc + c0;
        else                 src = Wv + (size_t)(grow - 64) * Cc + c0;
        float4 v0 = *(const float4*)src;
        float4 v1 = *(const float4*)(src + 4);
        bf16x8 o;
        o[0] = __bfloat16_as_short(__float2bfloat16(v0.x));
        o[1] = __bfloat16_as_short(__float2bfloat16(v0.y));
        o[2] = __bfloat16_as_short(__float2bfloat16(v0.z));
        o[3] = __bfloat16_as_short(__float2bfloat16(v0.w));
        o[4] = __bfloat16_as_short(__float2bfloat16(v1.x));
        o[5] = __bfloat16_as_short(__float2bfloat16(v1.y));
        o[6] = __bfloat16_as_short(__float2bfloat16(v1.z));
        o[7] = __bfloat16_as_short(__float2bfloat16(v1.w));
        int kchunk = c0 >> 5, qd = (c0 & 31) >> 3, cg = row >> 4, rl = row & 15;
        *(bf16x8*)(w_bf + ((size_t)ct * 32 + kchunk * 4 + cg) * 512 + (qd * 16 + rl) * 8) = o;
    }
}

// ---------------- proj v12: fused transpose(x)+stats + MFMA projection ----------
// v11 post-mortem: non-attn time 124 us vs ~55 us roofline -> dispatch gaps + the
// x_t 128MB round trip. v12 fuses convt into proj: per block, 4 c-quarter passes of
// convt's tile[64][68] transpose (float4 loads, bitwise-identical stats shuffles +
// atomics) writing ldsX's frag-block layout via ds_write_b128 (layout verified
// against the v11 glds16 mapping: frag=kchunk*4+ngrp, elem=(cquad*16+nlo)*8).
// x_t never materialized. MFMA ct-loop + stores byte-identical to v11.
__global__ __launch_bounds__(256, 2) void proj_kernel(
    const float* __restrict__ x, const __hip_bfloat16* __restrict__ w_bf,
    const float* __restrict__ bq, const float* __restrict__ bk, const float* __restrict__ bv,
    __hip_bfloat16* __restrict__ q_ws, __hip_bfloat16* __restrict__ k_ws,
    __hip_bfloat16* __restrict__ v_ws,
    float* __restrict__ sum_ws, float* __restrict__ sumsq_ws)
{
    __shared__ __hip_bfloat16 tile[64][68];
    __shared__ __hip_bfloat16 ldsX[32 * 512];
    __shared__ __hip_bfloat16 ldsW[32 * 512];

    const int n0 = blockIdx.x * 64;
    const int b  = blockIdx.y;
    const int t = threadIdx.x;
    const int w = t >> 6, lane = t & 63, quad = lane >> 4, l15 = lane & 15;

    // stage W(ct=0) early (DMA overlaps the transpose below)
#pragma unroll
    for (int j = 0; j < 8; j++) {
        int idx = w * 8 + j;
        glds16(w_bf + (size_t)idx * 512 + lane * 8, ldsW + idx * 512);
    }

    // ---- transpose x -> ldsX frag-block layout, fused stats (4 c-quarters) ----
    for (int cq = 0; cq < 4; cq++) {
#pragma unroll
        for (int i = 0; i < 1; i++) { /* keep structure parallel to convt */ }
#pragma unroll
        for (int i = 0; i < 1; i++) { }
        // pass 1: load 64c x 64n f32, convert, tile[c][n]; stats
#pragma unroll
        for (int i = 0; i < 4; i++) {
            int id = i * 256 + t;
            int row = id >> 4, col4 = id & 15;
            float4 v = *(const float4*)(x + ((size_t)(b * Cc + cq * 64 + row)) * Nn + n0 + col4 * 4);
            bf16x4 bv4;
            bv4[0] = __bfloat16_as_short(__float2bfloat16(v.x));
            bv4[1] = __bfloat16_as_short(__float2bfloat16(v.y));
            bv4[2] = __bfloat16_as_short(__float2bfloat16(v.z));
            bv4[3] = __bfloat16_as_short(__float2bfloat16(v.w));
            *(bf16x4*)((void*)&tile[row][col4 * 4]) = bv4;
            float ls  = v.x + v.y + v.z + v.w;
            float ls2 = v.x * v.x + v.y * v.y + v.z * v.z + v.w * v.w;
            ls  += __shfl_xor(ls, 1, 16);  ls2 += __shfl_xor(ls2, 1, 16);
            ls  += __shfl_xor(ls, 2, 16);  ls2 += __shfl_xor(ls2, 2, 16);
            ls  += __shfl_xor(ls, 4, 16);  ls2 += __shfl_xor(ls2, 4, 16);
            ls  += __shfl_xor(ls, 8, 16);  ls2 += __shfl_xor(ls2, 8, 16);
            if ((t & 15) == 0) {
                atomicAdd(&sum_ws[b * Cc + cq * 64 + row], ls);
                atomicAdd(&sumsq_ws[b * Cc + cq * 64 + row], ls2);
            }
        }
        __syncthreads();
        // pass 2: tile -> ldsX frag-block position (512 bf16x8 per quarter)
#pragma unroll
        for (int it = 0; it < 2; it++) {
            int id = it * 256 + t;
            int nl = id >> 3, cg = id & 7;
            bf16x8 o;
#pragma unroll
            for (int j = 0; j < 8; j++) o[j] = __bfloat16_as_short(tile[cg * 8 + j][nl]);
            int kchunk = cq * 2 + (cg >> 2);
            int cquad  = cg & 3;
            int ngrp = nl >> 4, nlo = nl & 15;
            *(bf16x8*)(ldsX + ((size_t)(kchunk * 4 + ngrp) * 512) + (cquad * 16 + nlo) * 8) = o;
        }
        __syncthreads();   // tile reused next quarter; last one also covers W DMA
    }

    // ---- MFMA ct-loop (byte-identical to v11) ----
    for (int ct = 0; ct < 5; ct++) {
        f32x4 acc[4];
#pragma unroll
        for (int cg = 0; cg < 4; cg++) {
            int gcol = ct * 64 + cg * 16 + l15;
            float bias = (gcol < 32) ? bq[gcol] : (gcol < 64 ? bk[gcol - 32] : bv[gcol - 64]);
            acc[cg] = (f32x4){bias, bias, bias, bias};
        }

#pragma unroll
        for (int kchunk = 0; kchunk < 8; kchunk++) {
            bf16x8 a = *(const bf16x8*)(ldsX + ((kchunk * 4 + w) * 64 + lane) * 8);
#pragma unroll
            for (int cg = 0; cg < 4; cg++) {
                bf16x8 bw = *(const bf16x8*)(ldsW + ((kchunk * 4 + cg) * 64 + lane) * 8);
                acc[cg] = __builtin_amdgcn_mfma_f32_16x16x32_bf16(a, bw, acc[cg], 0, 0, 0);
            }
        }

#pragma unroll
        for (int cg = 0; cg < 4; cg++) {
            int gcol = ct * 64 + cg * 16 + l15;
            int nb = n0 + w * 16 + quad * 4;
            if (gcol < 64) {
                __hip_bfloat16* dst = (gcol < 32) ? q_ws : k_ws;
                int d = gcol & 31;
#pragma unroll
                for (int r = 0; r < 4; r++)
                    dst[((size_t)(b * Nn + nb + r)) * Dd + d] = __float2bfloat16(acc[cg][r]);
            } else {
                int c = gcol - 64;
                bf16x4 o;
#pragma unroll
                for (int r = 0; r < 4; r++) o[r] = __bfloat16_as_short(__float2bfloat16(acc[cg][r]));
                *(bf16x4*)(v_ws + ((size_t)(b * Cc + c)) * Nn + nb) = o;
            }
        }

        if (ct < 4) {
            __syncthreads();   // all waves done reading ldsW(ct)
#pragma unroll
            for (int j = 0; j < 8; j++) {
                int idx = w * 8 + j;
                glds16(w_bf + ((size_t)(ct + 1) * 32 + idx) * 512 + lane * 8, ldsW + idx * 512);
            }
            __syncthreads();   // drain DMAs (vmcnt(0) at barrier)
        }
    }
}

// ---------------- flash attention v12: v10 loop + fused SE-gate prologue ----------
// Gate MLP computed per-block in a prologue (LDS scratch pre-staging); coef lives in
// the last 1KB of an enlarged 123904B LDS allocation (bytes 122880..123904 — never
// touched by V/K buffers [0..122880) or the epilogue exchange [0..69632)). Main loop
// byte-identical to verified v10.
__global__ __launch_bounds__(512, 1) void attn_kernel(
    const __hip_bfloat16* __restrict__ q_ws, const __hip_bfloat16* __restrict__ k_ws,
    const __hip_bfloat16* __restrict__ v_ws,
    const float* __restrict__ sum_ws, const float* __restrict__ sumsq_ws,
    const float* __restrict__ W1, const float* __restrict__ W2,
    const float* __restrict__ lamb_p,
    const float* __restrict__ x, const float* __restrict__ gamma_p,
    float* __restrict__ out)
{
    extern __shared__ __hip_bfloat16 smem[];
    // V: 3 x 16384 el (32 KB each); K: 3 x 4096 el (8 KB each); coef: last 1 KB
    __hip_bfloat16 *vcur = smem, *vnext = smem + 16384, *vnn = smem + 32768;
    __hip_bfloat16 *kA = smem + 49152, *kB = smem + 53248, *kC = smem + 57344;
    float* coef_s = (float*)((char*)smem + 122880);   // 256 f

    const int b  = blockIdx.x & 7;             // XCD-locality swizzle
    const int m0 = (blockIdx.x >> 3) * 128;
    const int t = threadIdx.x;
    const int w = t >> 6, lane = t & 63, quad = lane >> 4, l15 = lane & 15;
    const int p = w >> 2, pw = w & 3;          // n-parity, m-pair index

    // ---- fused SE gate (uses smem scratch that V-staging later overwrites) ----
    {
        float* inp_s = (float*)smem;           // 512 f
        float* h_s   = (float*)smem + 512;     // 32 f
        if (t < 256) {
            float s  = sum_ws[b * Cc + t];
            float s2 = sumsq_ws[b * Cc + t];
            float m   = s / Nn;
            float var = (s2 - (float)Nn * m * m) / (float)(Nn - 1);
            inp_s[t]       = m;
            inp_s[256 + t] = sqrtf(fmaxf(var, 0.f));
        }
        __syncthreads();
        {
            int r = t >> 4, s5 = t & 15;
            float a = 0.f;
#pragma unroll
            for (int i = 0; i < 32; i++) a += W1[r * 512 + s5 * 32 + i] * inp_s[s5 * 32 + i];
            a += __shfl_xor(a, 1, 16); a += __shfl_xor(a, 2, 16);
            a += __shfl_xor(a, 4, 16); a += __shfl_xor(a, 8, 16);
            if (s5 == 0) h_s[r] = fmaxf(a, 0.f);
        }
        __syncthreads();
        if (t < 256) {
            float gg = 0.f;
#pragma unroll
            for (int r = 0; r < 32; r++) gg += W2[t * 32 + r] * h_s[r];
            coef_s[t] = 1.f + lamb_p[0] * (1.f / (1.f + __expf(-gg)));
        }
        __syncthreads();
    }

    // Q fragments (B-operand) for this wave's 2 m-frags {2pw, 2pw+1}
    const bf16x8 aq0 = *(const bf16x8*)(q_ws + ((size_t)(b * Nn + m0 + (2 * pw)     * 16 + l15)) * Dd + quad * 8);
    const bf16x8 aq1 = *(const bf16x8*)(q_ws + ((size_t)(b * Nn + m0 + (2 * pw + 1) * 16 + l15)) * Dd + quad * 8);

    // V staging: wave w stages frags idx = w*4+j (idx = nchunk*16 + cfrag), linear LDS
    const __hip_bfloat16* vsrc[4];
#pragma unroll
    for (int j = 0; j < 4; j++) {
        int idx = w * 4 + j;
        int ch = idx >> 4, tc = idx & 15;
        vsrc[j] = v_ws + ((size_t)(b * Cc + tc * 16 + l15)) * Nn + ch * 32 + quad * 8;
    }
    // K staging with sigma row permutation (swap bits 2<->3 of l15); slab = 128 n rows
    const int sl15 = (l15 & 3) | ((l15 & 4) << 1) | ((l15 & 8) >> 1);
    const __hip_bfloat16* ksrc = k_ws + ((size_t)(b * Nn + w * 16 + sl15)) * Dd + quad * 8;

    // prestage V(0), V(1), K slab 0, K slab 1; full drain via __syncthreads
#pragma unroll
    for (int j = 0; j < 4; j++) glds16(vsrc[j], vcur + (w * 4 + j) * 512);
#pragma unroll
    for (int j = 0; j < 4; j++) glds16(vsrc[j] + 64, vnext + (w * 4 + j) * 512);
    glds16(ksrc, kA + w * 512);
    glds16(ksrc + (size_t)128 * Dd, kB + w * 512);
    __syncthreads();

    f32x4 acc[2][16];
#pragma unroll
    for (int i = 0; i < 2; i++)
#pragma unroll
        for (int j = 0; j < 16; j++) acc[i][j] = (f32x4){0.f, 0.f, 0.f, 0.f};
    float lsum0 = 0.f, lsum1 = 0.f;

    const int NIT = Nn / 64;

    // prologue: S(0) -> pc (current P regs) from kA half 0
    u32 pc0[2][2], pc1[2][2];
#pragma unroll
    for (int j = 0; j < 2; j++) {
        bf16x8 ak = *(const bf16x8*)(kA + ((2 * p + j) * 64 + lane) * 8);
        f32x4 s0 = __builtin_amdgcn_mfma_f32_16x16x32_bf16(ak, aq0, (f32x4){0.f,0.f,0.f,0.f}, 0, 0, 0);
        f32x4 s1 = __builtin_amdgcn_mfma_f32_16x16x32_bf16(ak, aq1, (f32x4){0.f,0.f,0.f,0.f}, 0, 0, 0);
        float a0 = __expf(s0[0]), a1 = __expf(s0[1]), a2 = __expf(s0[2]), a3 = __expf(s0[3]);
        lsum0 += (a0 + a1) + (a2 + a3);
        pc0[j][0] = pkbf16(a0, a1); pc0[j][1] = pkbf16(a2, a3);
        float b0 = __expf(s1[0]), b1 = __expf(s1[1]), b2 = __expf(s1[2]), b3 = __expf(s1[3]);
        lsum1 += (b0 + b1) + (b2 + b3);
        pc1[j][0] = pkbf16(b0, b1); pc1[j][1] = pkbf16(b2, b3);
    }

    for (int it = 0; it < NIT; it++) {
        // ---- prefetch: V(it+2) -> vnn; K slab (it/2)+2 -> kC (even iters) ----
        if (it + 2 < NIT) {
#pragma unroll
            for (int j = 0; j < 4; j++)
                glds16(vsrc[j] + (size_t)(it + 2) * 64, vnn + (w * 4 + j) * 512);
        }
        if ((it & 1) == 0 && (it >> 1) + 2 < 32)
            glds16(ksrc + (size_t)(((it >> 1) + 2) * 128) * Dd, kC + w * 512);

        // ---- B-frags for PV(it) from pc via permlane32_swap (nc = p) ----
        auto g0 = __builtin_amdgcn_permlane32_swap(pc0[0][0], pc0[1][0], false, false);
        auto g1 = __builtin_amdgcn_permlane32_swap(pc0[0][1], pc0[1][1], false, false);
        auto h0 = __builtin_amdgcn_permlane32_swap(pc1[0][0], pc1[1][0], false, false);
        auto h1 = __builtin_amdgcn_permlane32_swap(pc1[0][1], pc1[1][1], false, false);
        union { u32 uw[4]; bf16x8 v; } bp0, bp1;
        bp0.uw[0] = g0[0]; bp0.uw[1] = g1[0]; bp0.uw[2] = g0[1]; bp0.uw[3] = g1[1];
        bp1.uw[0] = h0[0]; bp1.uw[1] = h1[0]; bp1.uw[2] = h0[1]; bp1.uw[3] = h1[1];

        // ---- S(it+1) -> pn; overlaps PV below. kA holds slab it>>1, kB the next. ----
        u32 pn0[2][2], pn1[2][2];
        const int itn = (it + 1 < NIT) ? it + 1 : NIT - 1;
        const __hip_bfloat16* kb = (((itn >> 1) > (it >> 1)) ? kB : kA) + (itn & 1) * 2048;
        float nls0 = 0.f, nls1 = 0.f;
#pragma unroll
        for (int j = 0; j < 2; j++) {
            bf16x8 ak = *(const bf16x8*)(kb + ((2 * p + j) * 64 + lane) * 8);
            f32x4 s0 = __builtin_amdgcn_mfma_f32_16x16x32_bf16(ak, aq0, (f32x4){0.f,0.f,0.f,0.f}, 0, 0, 0);
            f32x4 s1 = __builtin_amdgcn_mfma_f32_16x16x32_bf16(ak, aq1, (f32x4){0.f,0.f,0.f,0.f}, 0, 0, 0);
            float a0 = __expf(s0[0]), a1 = __expf(s0[1]), a2 = __expf(s0[2]), a3 = __expf(s0[3]);
            nls0 += (a0 + a1) + (a2 + a3);
            pn0[j][0] = pkbf16(a0, a1); pn0[j][1] = pkbf16(a2, a3);
            float b0 = __expf(s1[0]), b1 = __expf(s1[1]), b2 = __expf(s1[2]), b3 = __expf(s1[3]);
            nls1 += (b0 + b1) + (b2 + b3);
            pn1[j][0] = pkbf16(b0, b1); pn1[j][1] = pkbf16(b2, b3);
        }
        if (it + 1 < NIT) { lsum0 += nls0; lsum1 += nls1; }

        // ---- O^T += V P^T over this wave's n-half (kc = p) ----
#pragma unroll
        for (int cf = 0; cf < 16; cf++) {
            bf16x8 av = *(const bf16x8*)(vcur + ((p * 16 + cf) * 64 + lane) * 8);
            acc[0][cf] = __builtin_amdgcn_mfma_f32_16x16x32_bf16(av, bp0.v, acc[0][cf], 0, 0, 0);
            acc[1][cf] = __builtin_amdgcn_mfma_f32_16x16x32_bf16(av, bp1.v, acc[1][cf], 0, 0, 0);
        }

        // rotate P regs
#pragma unroll
        for (int j = 0; j < 2; j++)
#pragma unroll
            for (int k = 0; k < 2; k++) { pc0[j][k] = pn0[j][k]; pc1[j][k] = pn1[j][k]; }

        // rotate buffers (register pointer swaps)
        { __hip_bfloat16* vt = vcur; vcur = vnext; vnext = vnn; vnn = vt; }
        if (it & 1) { __hip_bfloat16* kt = kA; kA = kB; kB = kC; kC = kt; }

        // ---- T4 barrier: counted vmcnt keeps this iter's prefetch in flight ----
        if (it + 2 < NIT)
            asm volatile("s_waitcnt vmcnt(4)\n\ts_barrier" ::: "memory");
        else
            asm volatile("s_waitcnt vmcnt(0)\n\ts_barrier" ::: "memory");
    }

    // ---- cross-parity reduction: (w, w^4) hold disjoint-n partials of same output.
    // ALL acc indices compile-time (rule #20): wave-uniform branches on p. ----
    float* lex = (float*)(smem + 32768);   // bytes 65536..69632 over dead LDS
    lex[w * 128 + lane]      = lsum0;
    lex[w * 128 + 64 + lane] = lsum1;
    f32x4* exv = (f32x4*)smem;             // bytes 0..65536 over dead LDS
#pragma unroll
    for (int mfi = 0; mfi < 2; mfi++) {
        __syncthreads();
        if (p == 0) {
#pragma unroll
            for (int j = 0; j < 8; j++) exv[(w * 8 + j) * 64 + lane] = acc[mfi][8 + j];
        } else {
#pragma unroll
            for (int j = 0; j < 8; j++) exv[(w * 8 + j) * 64 + lane] = acc[mfi][j];
        }
        __syncthreads();
        if (p == 0) {
#pragma unroll
            for (int j = 0; j < 8; j++) acc[mfi][j] += exv[((w ^ 4) * 8 + j) * 64 + lane];
        } else {
#pragma unroll
            for (int j = 0; j < 8; j++) acc[mfi][8 + j] += exv[((w ^ 4) * 8 + j) * 64 + lane];
        }
        if (mfi == 0) {
            lsum0 += lex[(w ^ 4) * 128 + lane];
            lsum1 += lex[(w ^ 4) * 128 + 64 + lane];
        }
    }

    // ---- epilogue: l[m] reduce over quads (m = l15 is lane-local), then store ----
    lsum0 += __shfl_xor(lsum0, 16); lsum0 += __shfl_xor(lsum0, 32);
    lsum1 += __shfl_xor(lsum1, 16); lsum1 += __shfl_xor(lsum1, 32);
    const float g = gamma_p[0];
    const float inv0 = g / lsum0, inv1 = g / lsum1;

    if (p == 0) {
#pragma unroll
        for (int j = 0; j < 8; j++) {
#pragma unroll
            for (int r = 0; r < 4; r++) {
                int c = j * 16 + quad * 4 + r;
                float cfv = coef_s[c];
                size_t base = ((size_t)(b * Cc + c)) * Nn + m0 + (2 * pw) * 16 + l15;
                out[base]      = acc[0][j][r] * inv0 + cfv * x[base];
                out[base + 16] = acc[1][j][r] * inv1 + cfv * x[base + 16];
            }
        }
    } else {
#pragma unroll
        for (int j = 0; j < 8; j++) {
#pragma unroll
            for (int r = 0; r < 4; r++) {
                int c = (8 + j) * 16 + quad * 4 + r;
                float cfv = coef_s[c];
                size_t base = ((size_t)(b * Cc + c)) * Nn + m0 + (2 * pw) * 16 + l15;
                out[base]      = acc[0][8 + j][r] * inv0 + cfv * x[base];
                out[base + 16] = acc[1][8 + j][r] * inv1 + cfv * x[base + 16];
            }
        }
    }
}

extern "C" void kernel_launch(void* const* d_in, const int* in_sizes, int n_in,
                              void* d_out, int out_size, void* d_ws, size_t ws_size,
                              hipStream_t stream) {
    const float* x     = (const float*)d_in[0];
    const float* Wq    = (const float*)d_in[1];
    const float* bq    = (const float*)d_in[2];
    const float* Wk    = (const float*)d_in[3];
    const float* bk    = (const float*)d_in[4];
    const float* Wv    = (const float*)d_in[5];
    const float* bv    = (const float*)d_in[6];
    const float* gamma = (const float*)d_in[7];
    const float* W1    = (const float*)d_in[8];
    const float* W2    = (const float*)d_in[9];
    const float* lamb  = (const float*)d_in[10];
    float* out = (float*)d_out;

    char* ws = (char*)d_ws;
    __hip_bfloat16* q_ws = (__hip_bfloat16*)ws;                       //  2 MB
    __hip_bfloat16* k_ws = (__hip_bfloat16*)(ws + (2u  << 20));       //  2 MB
    __hip_bfloat16* v_ws = (__hip_bfloat16*)(ws + (4u  << 20));       // 16 MB
    float* sum_ws   = (float*)(ws + (36u << 20));
    float* sumsq_ws = sum_ws + Bb * Cc;
    __hip_bfloat16* w_bf = (__hip_bfloat16*)(ws + (37u << 20));       // 320 KB

    (void)hipFuncSetAttribute((const void*)attn_kernel,
                              hipFuncAttributeMaxDynamicSharedMemorySize, 123904);

    wconv_kernel<<<5, 256, 0, stream>>>(Wq, Wk, Wv, w_bf, sum_ws);
    proj_kernel<<<dim3(Nn / 64, Bb), 256, 0, stream>>>(x, w_bf, bq, bk, bv,
                                                       q_ws, k_ws, v_ws, sum_ws, sumsq_ws);
    attn_kernel<<<256, 512, 123904, stream>>>(q_ws, k_ws, v_ws, sum_ws, sumsq_ws,
                                              W1, W2, lamb, x, gamma, out);
}

// Round 9
// 216.918 us; speedup vs baseline: 6.3872x; 1.0210x over previous
//
#include <hip/hip_runtime.h>
#include <hip/hip_bf16.h>

#define Bb 8
#define Cc 256
#define Nn 4096
#define Dd 32

typedef short bf16x8 __attribute__((ext_vector_type(8)));
typedef short bf16x4 __attribute__((ext_vector_type(4)));
typedef float f32x4 __attribute__((ext_vector_type(4)));
typedef unsigned int u32;

__device__ __forceinline__ void glds16(const void* g, void* l) {
    __builtin_amdgcn_global_load_lds(
        (const __attribute__((address_space(1))) unsigned int*)g,
        (__attribute__((address_space(3))) unsigned int*)l, 16, 0, 0);
}

// pack two f32 -> one u32 of 2 bf16 (low = a). Compiler fuses to v_cvt_pk_bf16_f32.
__device__ __forceinline__ u32 pkbf16(float a, float b) {
    return ((u32)__bfloat16_as_ushort(__float2bfloat16(b)) << 16) |
           (u32)__bfloat16_as_ushort(__float2bfloat16(a));
}

// ---------------- W -> bf16 frag-block layout + zero stats (runs first in stream) ----
__global__ __launch_bounds__(256) void wconv_kernel(
    const float* __restrict__ Wq, const float* __restrict__ Wk, const float* __restrict__ Wv,
    __hip_bfloat16* __restrict__ w_bf, float* __restrict__ stats /* 2*Bb*Cc floats */)
{
    const int ct = blockIdx.x;
    const int t = threadIdx.x;
    for (int k = ct * 256 + t; k < 2 * Bb * Cc; k += 5 * 256) stats[k] = 0.f;
#pragma unroll
    for (int i = 0; i < 8; i++) {
        int g = i * 256 + t;
        int row = g >> 5, c8 = g & 31;
        int c0 = c8 * 8;
        int grow = ct * 64 + row;
        const float* src;
        if (grow < 32)       src = Wq + (size_t)grow * Cc + c0;
        else if (grow < 64)  src = Wk + (size_t)(grow - 32) * Cc + c0;
        else                 src = Wv + (size_t)(grow - 64) * Cc + c0;
        float4 v0 = *(const float4*)src;
        float4 v1 = *(const float4*)(src + 4);
        bf16x8 o;
        o[0] = __bfloat16_as_short(__float2bfloat16(v0.x));
        o[1] = __bfloat16_as_short(__float2bfloat16(v0.y));
        o[2] = __bfloat16_as_short(__float2bfloat16(v0.z));
        o[3] = __bfloat16_as_short(__float2bfloat16(v0.w));
        o[4] = __bfloat16_as_short(__float2bfloat16(v1.x));
        o[5] = __bfloat16_as_short(__float2bfloat16(v1.y));
        o[6] = __bfloat16_as_short(__float2bfloat16(v1.z));
        o[7] = __bfloat16_as_short(__float2bfloat16(v1.w));
        int kchunk = c0 >> 5, qd = (c0 & 31) >> 3, cg = row >> 4, rl = row & 15;
        *(bf16x8*)(w_bf + ((size_t)ct * 32 + kchunk * 4 + cg) * 512 + (qd * 16 + rl) * 8) = o;
    }
}

// ---------------- proj v13: fused transpose+stats+MFMA, ALL x-loads hoisted ----------
// v12 post-mortem: each transpose quarter stalled on its own global loads between
// barriers (2 blocks/CU, little TLP). v13 issues all 16 float4 x-loads at kernel
// entry into registers (+64 VGPR, cap 256 @ 2 waves/SIMD); quarters then run
// back-to-back on register data. All LDS layouts / MFMA / stores byte-identical
// to v12 (verified).
__global__ __launch_bounds__(256, 2) void proj_kernel(
    const float* __restrict__ x, const __hip_bfloat16* __restrict__ w_bf,
    const float* __restrict__ bq, const float* __restrict__ bk, const float* __restrict__ bv,
    __hip_bfloat16* __restrict__ q_ws, __hip_bfloat16* __restrict__ k_ws,
    __hip_bfloat16* __restrict__ v_ws,
    float* __restrict__ sum_ws, float* __restrict__ sumsq_ws)
{
    __shared__ __hip_bfloat16 tile[64][68];
    __shared__ __hip_bfloat16 ldsX[32 * 512];
    __shared__ __hip_bfloat16 ldsW[32 * 512];

    const int n0 = blockIdx.x * 64;
    const int b  = blockIdx.y;
    const int t = threadIdx.x;
    const int w = t >> 6, lane = t & 63, quad = lane >> 4, l15 = lane & 15;

    // issue ALL x loads up front (4 quarters x 4 float4 per thread)
    float4 xv[4][4];
#pragma unroll
    for (int cq = 0; cq < 4; cq++)
#pragma unroll
        for (int i = 0; i < 4; i++) {
            int id = i * 256 + t;
            int row = id >> 4, col4 = id & 15;
            xv[cq][i] = *(const float4*)(x + ((size_t)(b * Cc + cq * 64 + row)) * Nn + n0 + col4 * 4);
        }

    // stage W(ct=0) (DMA overlaps the transpose below)
#pragma unroll
    for (int j = 0; j < 8; j++) {
        int idx = w * 8 + j;
        glds16(w_bf + (size_t)idx * 512 + lane * 8, ldsW + idx * 512);
    }

    // ---- transpose -> ldsX frag-block layout, fused stats (4 c-quarters) ----
#pragma unroll
    for (int cq = 0; cq < 4; cq++) {
#pragma unroll
        for (int i = 0; i < 4; i++) {
            int id = i * 256 + t;
            int row = id >> 4, col4 = id & 15;
            float4 v = xv[cq][i];
            bf16x4 bv4;
            bv4[0] = __bfloat16_as_short(__float2bfloat16(v.x));
            bv4[1] = __bfloat16_as_short(__float2bfloat16(v.y));
            bv4[2] = __bfloat16_as_short(__float2bfloat16(v.z));
            bv4[3] = __bfloat16_as_short(__float2bfloat16(v.w));
            *(bf16x4*)((void*)&tile[row][col4 * 4]) = bv4;
            float ls  = v.x + v.y + v.z + v.w;
            float ls2 = v.x * v.x + v.y * v.y + v.z * v.z + v.w * v.w;
            ls  += __shfl_xor(ls, 1, 16);  ls2 += __shfl_xor(ls2, 1, 16);
            ls  += __shfl_xor(ls, 2, 16);  ls2 += __shfl_xor(ls2, 2, 16);
            ls  += __shfl_xor(ls, 4, 16);  ls2 += __shfl_xor(ls2, 4, 16);
            ls  += __shfl_xor(ls, 8, 16);  ls2 += __shfl_xor(ls2, 8, 16);
            if ((t & 15) == 0) {
                atomicAdd(&sum_ws[b * Cc + cq * 64 + row], ls);
                atomicAdd(&sumsq_ws[b * Cc + cq * 64 + row], ls2);
            }
        }
        __syncthreads();
#pragma unroll
        for (int it = 0; it < 2; it++) {
            int id = it * 256 + t;
            int nl = id >> 3, cg = id & 7;
            bf16x8 o;
#pragma unroll
            for (int j = 0; j < 8; j++) o[j] = __bfloat16_as_short(tile[cg * 8 + j][nl]);
            int kchunk = cq * 2 + (cg >> 2);
            int cquad  = cg & 3;
            int ngrp = nl >> 4, nlo = nl & 15;
            *(bf16x8*)(ldsX + ((size_t)(kchunk * 4 + ngrp) * 512) + (cquad * 16 + nlo) * 8) = o;
        }
        __syncthreads();   // tile reused next quarter; last one also covers W DMA
    }

    // ---- MFMA ct-loop (byte-identical to v11/v12) ----
    for (int ct = 0; ct < 5; ct++) {
        f32x4 acc[4];
#pragma unroll
        for (int cg = 0; cg < 4; cg++) {
            int gcol = ct * 64 + cg * 16 + l15;
            float bias = (gcol < 32) ? bq[gcol] : (gcol < 64 ? bk[gcol - 32] : bv[gcol - 64]);
            acc[cg] = (f32x4){bias, bias, bias, bias};
        }

#pragma unroll
        for (int kchunk = 0; kchunk < 8; kchunk++) {
            bf16x8 a = *(const bf16x8*)(ldsX + ((kchunk * 4 + w) * 64 + lane) * 8);
#pragma unroll
            for (int cg = 0; cg < 4; cg++) {
                bf16x8 bw = *(const bf16x8*)(ldsW + ((kchunk * 4 + cg) * 64 + lane) * 8);
                acc[cg] = __builtin_amdgcn_mfma_f32_16x16x32_bf16(a, bw, acc[cg], 0, 0, 0);
            }
        }

#pragma unroll
        for (int cg = 0; cg < 4; cg++) {
            int gcol = ct * 64 + cg * 16 + l15;
            int nb = n0 + w * 16 + quad * 4;
            if (gcol < 64) {
                __hip_bfloat16* dst = (gcol < 32) ? q_ws : k_ws;
                int d = gcol & 31;
#pragma unroll
                for (int r = 0; r < 4; r++)
                    dst[((size_t)(b * Nn + nb + r)) * Dd + d] = __float2bfloat16(acc[cg][r]);
            } else {
                int c = gcol - 64;
                bf16x4 o;
#pragma unroll
                for (int r = 0; r < 4; r++) o[r] = __bfloat16_as_short(__float2bfloat16(acc[cg][r]));
                *(bf16x4*)(v_ws + ((size_t)(b * Cc + c)) * Nn + nb) = o;
            }
        }

        if (ct < 4) {
            __syncthreads();
#pragma unroll
            for (int j = 0; j < 8; j++) {
                int idx = w * 8 + j;
                glds16(w_bf + ((size_t)(ct + 1) * 32 + idx) * 512 + lane * 8, ldsW + idx * 512);
            }
            __syncthreads();
        }
    }
}

// ---------------- flash attention v13: v12 + conflict-free gate prologue ----------
// v12 post-mortem: gate's W1 loop read inp_s at 128B lane stride -> 16-way bank
// conflict (1.97M/dispatch, +3.2us). v13: lane (r,s5) sums over i*16+s5 (lane-
// contiguous; r-groups broadcast) -> 0 conflicts; W1 reads 64B-contiguous per 16
// lanes. Same math (same 512-sum per r, same 16-wide shfl reduce). Main loop
// byte-identical to verified v10/v11/v12.
__global__ __launch_bounds__(512, 1) void attn_kernel(
    const __hip_bfloat16* __restrict__ q_ws, const __hip_bfloat16* __restrict__ k_ws,
    const __hip_bfloat16* __restrict__ v_ws,
    const float* __restrict__ sum_ws, const float* __restrict__ sumsq_ws,
    const float* __restrict__ W1, const float* __restrict__ W2,
    const float* __restrict__ lamb_p,
    const float* __restrict__ x, const float* __restrict__ gamma_p,
    float* __restrict__ out)
{
    extern __shared__ __hip_bfloat16 smem[];
    __hip_bfloat16 *vcur = smem, *vnext = smem + 16384, *vnn = smem + 32768;
    __hip_bfloat16 *kA = smem + 49152, *kB = smem + 53248, *kC = smem + 57344;
    float* coef_s = (float*)((char*)smem + 122880);   // 256 f

    const int b  = blockIdx.x & 7;             // XCD-locality swizzle
    const int m0 = (blockIdx.x >> 3) * 128;
    const int t = threadIdx.x;
    const int w = t >> 6, lane = t & 63, quad = lane >> 4, l15 = lane & 15;
    const int p = w >> 2, pw = w & 3;          // n-parity, m-pair index

    // ---- fused SE gate (conflict-free) ----
    {
        float* inp_s = (float*)smem;           // 512 f
        float* h_s   = (float*)smem + 512;     // 32 f
        if (t < 256) {
            float s  = sum_ws[b * Cc + t];
            float s2 = sumsq_ws[b * Cc + t];
            float m   = s / Nn;
            float var = (s2 - (float)Nn * m * m) / (float)(Nn - 1);
            inp_s[t]       = m;
            inp_s[256 + t] = sqrtf(fmaxf(var, 0.f));
        }
        __syncthreads();
        {
            int r = t >> 4, s5 = t & 15;
            float a = 0.f;
#pragma unroll
            for (int i = 0; i < 32; i++) a += W1[r * 512 + i * 16 + s5] * inp_s[i * 16 + s5];
            a += __shfl_xor(a, 1, 16); a += __shfl_xor(a, 2, 16);
            a += __shfl_xor(a, 4, 16); a += __shfl_xor(a, 8, 16);
            if (s5 == 0) h_s[r] = fmaxf(a, 0.f);
        }
        __syncthreads();
        if (t < 256) {
            float gg = 0.f;
#pragma unroll
            for (int r = 0; r < 32; r++) gg += W2[t * 32 + r] * h_s[r];
            coef_s[t] = 1.f + lamb_p[0] * (1.f / (1.f + __expf(-gg)));
        }
        __syncthreads();
    }

    // Q fragments (B-operand) for this wave's 2 m-frags {2pw, 2pw+1}
    const bf16x8 aq0 = *(const bf16x8*)(q_ws + ((size_t)(b * Nn + m0 + (2 * pw)     * 16 + l15)) * Dd + quad * 8);
    const bf16x8 aq1 = *(const bf16x8*)(q_ws + ((size_t)(b * Nn + m0 + (2 * pw + 1) * 16 + l15)) * Dd + quad * 8);

    // V staging: wave w stages frags idx = w*4+j (idx = nchunk*16 + cfrag), linear LDS
    const __hip_bfloat16* vsrc[4];
#pragma unroll
    for (int j = 0; j < 4; j++) {
        int idx = w * 4 + j;
        int ch = idx >> 4, tc = idx & 15;
        vsrc[j] = v_ws + ((size_t)(b * Cc + tc * 16 + l15)) * Nn + ch * 32 + quad * 8;
    }
    // K staging with sigma row permutation (swap bits 2<->3 of l15); slab = 128 n rows
    const int sl15 = (l15 & 3) | ((l15 & 4) << 1) | ((l15 & 8) >> 1);
    const __hip_bfloat16* ksrc = k_ws + ((size_t)(b * Nn + w * 16 + sl15)) * Dd + quad * 8;

    // prestage V(0), V(1), K slab 0, K slab 1; full drain via __syncthreads
#pragma unroll
    for (int j = 0; j < 4; j++) glds16(vsrc[j], vcur + (w * 4 + j) * 512);
#pragma unroll
    for (int j = 0; j < 4; j++) glds16(vsrc[j] + 64, vnext + (w * 4 + j) * 512);
    glds16(ksrc, kA + w * 512);
    glds16(ksrc + (size_t)128 * Dd, kB + w * 512);
    __syncthreads();

    f32x4 acc[2][16];
#pragma unroll
    for (int i = 0; i < 2; i++)
#pragma unroll
        for (int j = 0; j < 16; j++) acc[i][j] = (f32x4){0.f, 0.f, 0.f, 0.f};
    float lsum0 = 0.f, lsum1 = 0.f;

    const int NIT = Nn / 64;

    // prologue: S(0) -> pc (current P regs) from kA half 0
    u32 pc0[2][2], pc1[2][2];
#pragma unroll
    for (int j = 0; j < 2; j++) {
        bf16x8 ak = *(const bf16x8*)(kA + ((2 * p + j) * 64 + lane) * 8);
        f32x4 s0 = __builtin_amdgcn_mfma_f32_16x16x32_bf16(ak, aq0, (f32x4){0.f,0.f,0.f,0.f}, 0, 0, 0);
        f32x4 s1 = __builtin_amdgcn_mfma_f32_16x16x32_bf16(ak, aq1, (f32x4){0.f,0.f,0.f,0.f}, 0, 0, 0);
        float a0 = __expf(s0[0]), a1 = __expf(s0[1]), a2 = __expf(s0[2]), a3 = __expf(s0[3]);
        lsum0 += (a0 + a1) + (a2 + a3);
        pc0[j][0] = pkbf16(a0, a1); pc0[j][1] = pkbf16(a2, a3);
        float b0 = __expf(s1[0]), b1 = __expf(s1[1]), b2 = __expf(s1[2]), b3 = __expf(s1[3]);
        lsum1 += (b0 + b1) + (b2 + b3);
        pc1[j][0] = pkbf16(b0, b1); pc1[j][1] = pkbf16(b2, b3);
    }

    for (int it = 0; it < NIT; it++) {
        // ---- prefetch: V(it+2) -> vnn; K slab (it/2)+2 -> kC (even iters) ----
        if (it + 2 < NIT) {
#pragma unroll
            for (int j = 0; j < 4; j++)
                glds16(vsrc[j] + (size_t)(it + 2) * 64, vnn + (w * 4 + j) * 512);
        }
        if ((it & 1) == 0 && (it >> 1) + 2 < 32)
            glds16(ksrc + (size_t)(((it >> 1) + 2) * 128) * Dd, kC + w * 512);

        // ---- B-frags for PV(it) from pc via permlane32_swap (nc = p) ----
        auto g0 = __builtin_amdgcn_permlane32_swap(pc0[0][0], pc0[1][0], false, false);
        auto g1 = __builtin_amdgcn_permlane32_swap(pc0[0][1], pc0[1][1], false, false);
        auto h0 = __builtin_amdgcn_permlane32_swap(pc1[0][0], pc1[1][0], false, false);
        auto h1 = __builtin_amdgcn_permlane32_swap(pc1[0][1], pc1[1][1], false, false);
        union { u32 uw[4]; bf16x8 v; } bp0, bp1;
        bp0.uw[0] = g0[0]; bp0.uw[1] = g1[0]; bp0.uw[2] = g0[1]; bp0.uw[3] = g1[1];
        bp1.uw[0] = h0[0]; bp1.uw[1] = h1[0]; bp1.uw[2] = h0[1]; bp1.uw[3] = h1[1];

        // ---- S(it+1) -> pn; overlaps PV below. kA holds slab it>>1, kB the next. ----
        u32 pn0[2][2], pn1[2][2];
        const int itn = (it + 1 < NIT) ? it + 1 : NIT - 1;
        const __hip_bfloat16* kb = (((itn >> 1) > (it >> 1)) ? kB : kA) + (itn & 1) * 2048;
        float nls0 = 0.f, nls1 = 0.f;
#pragma unroll
        for (int j = 0; j < 2; j++) {
            bf16x8 ak = *(const bf16x8*)(kb + ((2 * p + j) * 64 + lane) * 8);
            f32x4 s0 = __builtin_amdgcn_mfma_f32_16x16x32_bf16(ak, aq0, (f32x4){0.f,0.f,0.f,0.f}, 0, 0, 0);
            f32x4 s1 = __builtin_amdgcn_mfma_f32_16x16x32_bf16(ak, aq1, (f32x4){0.f,0.f,0.f,0.f}, 0, 0, 0);
            float a0 = __expf(s0[0]), a1 = __expf(s0[1]), a2 = __expf(s0[2]), a3 = __expf(s0[3]);
            nls0 += (a0 + a1) + (a2 + a3);
            pn0[j][0] = pkbf16(a0, a1); pn0[j][1] = pkbf16(a2, a3);
            float b0 = __expf(s1[0]), b1 = __expf(s1[1]), b2 = __expf(s1[2]), b3 = __expf(s1[3]);
            nls1 += (b0 + b1) + (b2 + b3);
            pn1[j][0] = pkbf16(b0, b1); pn1[j][1] = pkbf16(b2, b3);
        }
        if (it + 1 < NIT) { lsum0 += nls0; lsum1 += nls1; }

        // ---- O^T += V P^T over this wave's n-half (kc = p) ----
#pragma unroll
        for (int cf = 0; cf < 16; cf++) {
            bf16x8 av = *(const bf16x8*)(vcur + ((p * 16 + cf) * 64 + lane) * 8);
            acc[0][cf] = __builtin_amdgcn_mfma_f32_16x16x32_bf16(av, bp0.v, acc[0][cf], 0, 0, 0);
            acc[1][cf] = __builtin_amdgcn_mfma_f32_16x16x32_bf16(av, bp1.v, acc[1][cf], 0, 0, 0);
        }

        // rotate P regs
#pragma unroll
        for (int j = 0; j < 2; j++)
#pragma unroll
            for (int k = 0; k < 2; k++) { pc0[j][k] = pn0[j][k]; pc1[j][k] = pn1[j][k]; }

        // rotate buffers (register pointer swaps)
        { __hip_bfloat16* vt = vcur; vcur = vnext; vnext = vnn; vnn = vt; }
        if (it & 1) { __hip_bfloat16* kt = kA; kA = kB; kB = kC; kC = kt; }

        // ---- T4 barrier: counted vmcnt keeps this iter's prefetch in flight ----
        if (it + 2 < NIT)
            asm volatile("s_waitcnt vmcnt(4)\n\ts_barrier" ::: "memory");
        else
            asm volatile("s_waitcnt vmcnt(0)\n\ts_barrier" ::: "memory");
    }

    // ---- cross-parity reduction: (w, w^4) hold disjoint-n partials of same output.
    // ALL acc indices compile-time (rule #20): wave-uniform branches on p. ----
    float* lex = (float*)(smem + 32768);   // bytes 65536..69632 over dead LDS
    lex[w * 128 + lane]      = lsum0;
    lex[w * 128 + 64 + lane] = lsum1;
    f32x4* exv = (f32x4*)smem;             // bytes 0..65536 over dead LDS
#pragma unroll
    for (int mfi = 0; mfi < 2; mfi++) {
        __syncthreads();
        if (p == 0) {
#pragma unroll
            for (int j = 0; j < 8; j++) exv[(w * 8 + j) * 64 + lane] = acc[mfi][8 + j];
        } else {
#pragma unroll
            for (int j = 0; j < 8; j++) exv[(w * 8 + j) * 64 + lane] = acc[mfi][j];
        }
        __syncthreads();
        if (p == 0) {
#pragma unroll
            for (int j = 0; j < 8; j++) acc[mfi][j] += exv[((w ^ 4) * 8 + j) * 64 + lane];
        } else {
#pragma unroll
            for (int j = 0; j < 8; j++) acc[mfi][8 + j] += exv[((w ^ 4) * 8 + j) * 64 + lane];
        }
        if (mfi == 0) {
            lsum0 += lex[(w ^ 4) * 128 + lane];
            lsum1 += lex[(w ^ 4) * 128 + 64 + lane];
        }
    }

    // ---- epilogue: l[m] reduce over quads (m = l15 is lane-local), then store ----
    lsum0 += __shfl_xor(lsum0, 16); lsum0 += __shfl_xor(lsum0, 32);
    lsum1 += __shfl_xor(lsum1, 16); lsum1 += __shfl_xor(lsum1, 32);
    const float g = gamma_p[0];
    const float inv0 = g / lsum0, inv1 = g / lsum1;

    if (p == 0) {
#pragma unroll
        for (int j = 0; j < 8; j++) {
#pragma unroll
            for (int r = 0; r < 4; r++) {
                int c = j * 16 + quad * 4 + r;
                float cfv = coef_s[c];
                size_t base = ((size_t)(b * Cc + c)) * Nn + m0 + (2 * pw) * 16 + l15;
                out[base]      = acc[0][j][r] * inv0 + cfv * x[base];
                out[base + 16] = acc[1][j][r] * inv1 + cfv * x[base + 16];
            }
        }
    } else {
#pragma unroll
        for (int j = 0; j < 8; j++) {
#pragma unroll
            for (int r = 0; r < 4; r++) {
                int c = (8 + j) * 16 + quad * 4 + r;
                float cfv = coef_s[c];
                size_t base = ((size_t)(b * Cc + c)) * Nn + m0 + (2 * pw) * 16 + l15;
                out[base]      = acc[0][8 + j][r] * inv0 + cfv * x[base];
                out[base + 16] = acc[1][8 + j][r] * inv1 + cfv * x[base + 16];
            }
        }
    }
}

extern "C" void kernel_launch(void* const* d_in, const int* in_sizes, int n_in,
                              void* d_out, int out_size, void* d_ws, size_t ws_size,
                              hipStream_t stream) {
    const float* x     = (const float*)d_in[0];
    const float* Wq    = (const float*)d_in[1];
    const float* bq    = (const float*)d_in[2];
    const float* Wk    = (const float*)d_in[3];
    const float* bk    = (const float*)d_in[4];
    const float* Wv    = (const float*)d_in[5];
    const float* bv    = (const float*)d_in[6];
    const float* gamma = (const float*)d_in[7];
    const float* W1    = (const float*)d_in[8];
    const float* W2    = (const float*)d_in[9];
    const float* lamb  = (const float*)d_in[10];
    float* out = (float*)d_out;

    char* ws = (char*)d_ws;
    __hip_bfloat16* q_ws = (__hip_bfloat16*)ws;                       //  2 MB
    __hip_bfloat16* k_ws = (__hip_bfloat16*)(ws + (2u  << 20));       //  2 MB
    __hip_bfloat16* v_ws = (__hip_bfloat16*)(ws + (4u  << 20));       // 16 MB
    float* sum_ws   = (float*)(ws + (36u << 20));
    float* sumsq_ws = sum_ws + Bb * Cc;
    __hip_bfloat16* w_bf = (__hip_bfloat16*)(ws + (37u << 20));       // 320 KB

    (void)hipFuncSetAttribute((const void*)attn_kernel,
                              hipFuncAttributeMaxDynamicSharedMemorySize, 123904);

    wconv_kernel<<<5, 256, 0, stream>>>(Wq, Wk, Wv, w_bf, sum_ws);
    proj_kernel<<<dim3(Nn / 64, Bb), 256, 0, stream>>>(x, w_bf, bq, bk, bv,
                                                       q_ws, k_ws, v_ws, sum_ws, sumsq_ws);
    attn_kernel<<<256, 512, 123904, stream>>>(q_ws, k_ws, v_ws, sum_ws, sumsq_ws,
                                              W1, W2, lamb, x, gamma, out);
}